// Round 6
// baseline (1425.230 us; speedup 1.0000x reference)
//
#include <hip/hip_runtime.h>
#include <string.h>

typedef unsigned short u16;
typedef unsigned int   u32;
typedef __attribute__((ext_vector_type(8))) short short8;     // 8 bf16/fp16 = 4 VGPRs
typedef __attribute__((ext_vector_type(4))) float f32x4;
typedef __attribute__((ext_vector_type(16))) float f32x16;
typedef __attribute__((ext_vector_type(2))) __fp16 h2;
typedef __attribute__((ext_vector_type(8))) __fp16 h8;
typedef __attribute__((ext_vector_type(2))) unsigned int u32x2;

// ---------- helpers ----------
__device__ __forceinline__ u16 f2b(float f) {                 // fp32 -> bf16 (RNE)
  u32 u = __float_as_uint(f);
  u32 r = (u + 0x7fffu + ((u >> 16) & 1u)) >> 16;
  return (u16)r;
}
// async global->LDS, 16B per lane; LDS dest = wave-uniform base + lane*16
__device__ __forceinline__ void cp16(const u16* g, u16* l) {
  __builtin_amdgcn_global_load_lds(
      (const __attribute__((address_space(1))) void*)g,
      (__attribute__((address_space(3))) void*)l, 16, 0, 0);
}
// v_permlane32_swap: a' = {a.lo32 | b.lo32}, b' = {a.hi32 | b.hi32}
__device__ __forceinline__ void plswap(u32& a, u32& b) {
  u32x2 r = __builtin_amdgcn_permlane32_swap(a, b, false, false);
  a = r[0]; b = r[1];
}

// ---------- fp32 -> bf16 conversion ----------
__global__ __launch_bounds__(256) void cvt_f2b_kernel(const float* __restrict__ in,
                                                      u16* __restrict__ out, int n) {
  int i = (blockIdx.x * 256 + threadIdx.x) * 4;
  if (i + 3 < n) {
    float4 v = *(const float4*)&in[i];
    ushort4 o = make_ushort4(f2b(v.x), f2b(v.y), f2b(v.z), f2b(v.w));
    *(ushort4*)&out[i] = o;
  }
}
// 4 weight matrices in one launch (blockIdx.y selects)
__global__ __launch_bounds__(256) void cvtw_kernel(const float* __restrict__ w0,
                                                   const float* __restrict__ w1,
                                                   const float* __restrict__ w2,
                                                   const float* __restrict__ w3,
                                                   u16* __restrict__ out) {
  const float* src = (blockIdx.y == 0) ? w0 : (blockIdx.y == 1) ? w1
                   : (blockIdx.y == 2) ? w2 : w3;
  int i = (blockIdx.x * 256 + threadIdx.x) * 4;
  float4 v = *(const float4*)&src[i];
  ushort4 o = make_ushort4(f2b(v.x), f2b(v.y), f2b(v.z), f2b(v.w));
  *(ushort4*)&out[(size_t)blockIdx.y * 1048576 + i] = o;
}

// ---------- bias4 expansion: gb4[h][j] = {bt[j-3..j]} * log2(e), clamped ----------
__global__ __launch_bounds__(256) void bias4x_kernel(const float* __restrict__ bt,
                                                     f32x4* __restrict__ gb4) {
  int idx = blockIdx.x * 256 + threadIdx.x;   // grid 256 -> 65536 = 16 heads x 4096
  int h = idx >> 12, j = idx & 4095;
  f32x4 v;
  #pragma unroll
  for (int e = 0; e < 4; ++e) {
    int r = j - 3 + e;
    r = r < 0 ? 0 : (r > 4094 ? 4094 : r);
    v[e] = bt[r * 16 + h] * 1.44269504f;
  }
  gb4[idx] = v;
}

// ---------- bf16 MFMA GEMM, BK=32, single-barrier dbuf pipeline (r3 version) ----------
template<int MODE>
__global__ __launch_bounds__(256) void gemm128_bt(
    const u16* __restrict__ A, const u16* __restrict__ Bw,
    void* __restrict__ outp, const float* __restrict__ bias,
    const int M, const int N, const int K) {
  __shared__ __attribute__((aligned(16))) u16 As[2][128 * 32];
  __shared__ __attribute__((aligned(16))) u16 Bs[2][128 * 32];

  const u16* Bw2 = Bw;
  if (MODE == 0) Bw2 += ((size_t)blockIdx.z) << 20;

  const int tid  = threadIdx.x;
  const int wave = tid >> 6, lane = tid & 63;
  const int quad = lane >> 4, l15 = lane & 15;
  const int wm   = (wave >> 1) * 64, wn = (wave & 1) * 64;
  const int m0   = blockIdx.x * 128, n0 = blockIdx.y * 128;

  const int srow = wave * 32 + (lane >> 2);
  const int scol = (lane & 3) * 8;
  const u16* gA0 = A   + (size_t)(m0 + srow) * K + scol;
  const u16* gA1 = gA0 + (size_t)16 * K;
  const u16* gB0 = Bw2 + (size_t)(n0 + srow) * K + scol;
  const u16* gB1 = gB0 + (size_t)16 * K;
  const int lo0 = (wave * 32) * 32, lo1 = (wave * 32 + 16) * 32;

  cp16(gA0, &As[0][lo0]); cp16(gA1, &As[0][lo1]);
  cp16(gB0, &Bs[0][lo0]); cp16(gB1, &Bs[0][lo1]);
  gA0 += 32; gA1 += 32; gB0 += 32; gB1 += 32;

  f32x4 acc[4][4] = {};
  const int nk = K >> 5;
  for (int kt = 0; kt < nk; ++kt) {
    const int cur = kt & 1;
    __syncthreads();
    if (kt + 1 < nk) {
      cp16(gA0, &As[1 - cur][lo0]); cp16(gA1, &As[1 - cur][lo1]);
      cp16(gB0, &Bs[1 - cur][lo0]); cp16(gB1, &Bs[1 - cur][lo1]);
      gA0 += 32; gA1 += 32; gB0 += 32; gB1 += 32;
    }
    short8 af[4], bf[4];
    #pragma unroll
    for (int mi = 0; mi < 4; ++mi)
      af[mi] = *(const short8*)&As[cur][(wm + mi * 16 + l15) * 32 + quad * 8];
    #pragma unroll
    for (int ni = 0; ni < 4; ++ni)
      bf[ni] = *(const short8*)&Bs[cur][(wn + ni * 16 + l15) * 32 + quad * 8];
    #pragma unroll
    for (int mi = 0; mi < 4; ++mi)
      #pragma unroll
      for (int ni = 0; ni < 4; ++ni)
        acc[mi][ni] = __builtin_amdgcn_mfma_f32_16x16x32_bf16(af[mi], bf[ni], acc[mi][ni], 0, 0, 0);
  }

  #pragma unroll
  for (int mi = 0; mi < 4; ++mi)
    #pragma unroll
    for (int ni = 0; ni < 4; ++ni) {
      if (MODE == 0 && blockIdx.z == 2) {
        int mb = m0 + wm + mi * 16 + quad * 4;
        int n  = n0 + wn + ni * 16 + l15;
        int b = mb >> 11, s = mb & 2047, h = n >> 6, d = n & 63;
        u16* out = (u16*)outp + (((size_t)2) << 23);
        h2 p0 = __builtin_amdgcn_cvt_pkrtz(acc[mi][ni][0], acc[mi][ni][1]);
        h2 p1 = __builtin_amdgcn_cvt_pkrtz(acc[mi][ni][2], acc[mi][ni][3]);
        ushort4 o;
        memcpy(&o.x, &p0, 4);
        memcpy(&o.z, &p1, 4);
        *(ushort4*)&out[((((size_t)b * 16 + h) * 64 + d) << 11) + s] = o;
      } else {
        #pragma unroll
        for (int r = 0; r < 4; ++r) {
          int m = m0 + wm + mi * 16 + quad * 4 + r;
          int n = n0 + wn + ni * 16 + l15;
          float v = acc[mi][ni][r];
          if (MODE == 0) {
            int b = m >> 11, s = m & 2047, h = n >> 6, d = n & 63;
            u16* out = (u16*)outp + (((size_t)blockIdx.z) << 23);
            out[((((size_t)b * 16 + h) * 2048 + s) << 6) + d] = f2b(v);
          } else {
            ((float*)outp)[(size_t)m * N + n] = v + bias[n];
          }
        }
      }
    }
}

// ---------- MFMA flash attention, 32x32x16, in-block split-K (2 k-groups) ----------
// r6 = r5 with the bias index fix: gb4[J] = {bt[J-3..J]} (window ENDING at J), so
// the base must be +2047 (was +2044 -- r3's window STARTED at the index, off-by-3).
// 512 threads = 8 waves = 2 k-groups x 4 q-waves; group g: k in [g*1024, g*1024+1024).
__global__ __launch_bounds__(512, 4) void attn_mfma_kernel(
    const u16* __restrict__ qb, const u16* __restrict__ kb, const u16* __restrict__ vtb,
    const f32x4* __restrict__ gb4, u16* __restrict__ ctx) {
  __shared__ __attribute__((aligned(16))) u16 smem[32768];   // 64KB: Ks[g][buf] + Vs[g][buf]
  __shared__ float sL[2][256];

  const int tid  = threadIdx.x;
  const int wave = tid >> 6, lane = tid & 63;
  const int wg   = wave >> 2, wv = wave & 3;   // k-group, q-wave
  const int l31  = lane & 31, hi = lane >> 5;
  const int xsw  = l31 & 7;
  const int bh   = blockIdx.x, h = bh & 15, b = bh >> 4;
  const int q0   = blockIdx.y * 256;

  u16* Ks0 = smem + (wg * 2) * 4096;            // + buf*4096
  u16* Vs0 = smem + 16384 + (wg * 2) * 4096;    // + buf*4096

  // Q B-frags: n = q, k(=d) = ks*16 + hi*8 + j
  short8 aQ[2][4];
  #pragma unroll
  for (int qs = 0; qs < 2; ++qs)
    #pragma unroll
    for (int ks = 0; ks < 4; ++ks)
      aQ[qs][ks] = *(const short8*)&qb[((size_t)bh * 2048 + q0 + wv * 64 + qs * 32 + l31) * 64
                                       + ks * 16 + hi * 8];

  f32x16 accO[2][2] = {};   // [qs][dt]; row d = (r&3)+8*(r>>2)+4*hi+32*dt, col q = l31
  f32x16 accL[2]    = {};   // lsum via ones-MFMA; accL[qs][0] = group k-sum for col q

  const h8 ones8 = {(__fp16)1.f, (__fp16)1.f, (__fp16)1.f, (__fp16)1.f,
                    (__fp16)1.f, (__fp16)1.f, (__fp16)1.f, (__fp16)1.f};

  // K staging (global_load_lds, pre-swizzled global source); group row offset wg*1024
  const int krow = lane >> 3;
  const int kchk = (lane & 7) ^ krow;
  const u16* kbase = kb + (((size_t)bh * 2048 + (wg << 10)) << 6);

  // V staging via regs -> swizzled LDS writes (per-group 256 threads)
  const int tg = tid & 255;
  const int srow = tg >> 2, t0 = tg & 3, ssw = srow & 7;
  const u16* vrow = vtb + (((size_t)bh * 64 + srow) << 11) + (wg << 10) + t0 * 16;
  const int vo0 = srow * 64 + (((2 * t0    ) ^ ssw) << 3);
  const int vo1 = srow * 64 + (((2 * t0 + 1) ^ ssw) << 3);

  const f32x4* gb = gb4 + (h << 12);

  // prologue: stage tile 0, prefetch tile 1 regs
  short8 vpre0 = *(const short8*)&vrow[0];
  short8 vpre1 = *(const short8*)&vrow[8];
  *(short8*)&Vs0[vo0] = vpre0;           // compiler inserts vmcnt wait
  *(short8*)&Vs0[vo1] = vpre1;
  #pragma unroll
  for (int g = 0; g < 2; ++g)
    cp16(kbase + (size_t)(wv * 16 + g * 8 + krow) * 64 + kchk * 8,
         &Ks0[(wv * 16 + g * 8) * 64]);
  vpre0 = *(const short8*)&vrow[64];
  vpre1 = *(const short8*)&vrow[72];

  for (int kt = 0; kt < 16; ++kt) {
    const int cur = kt & 1;
    __syncthreads();   // drains cp16(kt) + vpre loads; makes Vs[cur] writes visible
    if (kt < 15) {
      #pragma unroll
      for (int g = 0; g < 2; ++g)
        cp16(kbase + (size_t)((kt + 1) * 64 + wv * 16 + g * 8 + krow) * 64 + kchk * 8,
             &Ks0[(1 - cur) * 4096 + (wv * 16 + g * 8) * 64]);
      *(short8*)&Vs0[(1 - cur) * 4096 + vo0] = vpre0;   // V(kt+1), already landed
      *(short8*)&Vs0[(1 - cur) * 4096 + vo1] = vpre1;
      if (kt < 14) {
        const u16* vp = vrow + ((size_t)(kt + 2) << 6);
        vpre0 = *(const short8*)&vp[0];
        vpre1 = *(const short8*)&vp[8];
      }
    }

    #pragma unroll
    for (int t = 0; t < 2; ++t) {
      // ---- S^T tile t: rows k = t*32 + row(r,hi), cols q; aK shared across qs ----
      short8 aK[4];
      #pragma unroll
      for (int ks = 0; ks < 4; ++ks)
        aK[ks] = *(const short8*)&Ks0[cur * 4096 + (t * 32 + l31) * 64
                                      + (((ks * 2 + hi) ^ xsw) << 3)];
      f32x16 accS[2] = {};
      __builtin_amdgcn_s_setprio(1);
      #pragma unroll
      for (int ks = 0; ks < 4; ++ks)
        #pragma unroll
        for (int qs = 0; qs < 2; ++qs)
          accS[qs] = __builtin_amdgcn_mfma_f32_32x32x16_bf16(aK[ks], aQ[qs][ks], accS[qs], 0, 0, 0);
      __builtin_amdgcn_s_setprio(0);

      // ---- softmax: p = exp2(S*log2e/8 + bias*log2e); one global b128 bias read/rg ----
      // accS elem r=4rg+j sits at k-row (j + 8rg + 4hi); needed bt index = q-k+2047.
      // gb4[J] = {bt[J-3..J]}, usage bb4[3-j] -> J = base - 8rg with base ending +2047.
      u32 d[2][8];
      #pragma unroll
      for (int qs = 0; qs < 2; ++qs) {
        const int ibJ = q0 + wv * 64 + qs * 32 + l31 - (wg << 10) - kt * 64 - t * 32 - 4 * hi + 2047;
        #pragma unroll
        for (int rg = 0; rg < 4; ++rg) {
          const f32x4 bb4 = gb[ibJ - 8 * rg];   // [0]=bt(J-3) .. [3]=bt(J)
          float p0 = __builtin_amdgcn_exp2f(fmaf(accS[qs][4 * rg + 0], 0.18033688f, bb4[3]));
          float p1 = __builtin_amdgcn_exp2f(fmaf(accS[qs][4 * rg + 1], 0.18033688f, bb4[2]));
          float p2 = __builtin_amdgcn_exp2f(fmaf(accS[qs][4 * rg + 2], 0.18033688f, bb4[1]));
          float p3 = __builtin_amdgcn_exp2f(fmaf(accS[qs][4 * rg + 3], 0.18033688f, bb4[0]));
          h2 e0; e0[0] = (__fp16)p0; e0[1] = (__fp16)p1;
          h2 e1; e1[0] = (__fp16)p2; e1[1] = (__fp16)p3;
          memcpy(&d[qs][2 * rg],     &e0, 4);
          memcpy(&d[qs][2 * rg + 1], &e1, 4);
        }
      }

      // ---- PV + lsum: V reads shared across qs; lsum on MFMA pipe ----
      #pragma unroll
      for (int sl = 0; sl < 2; ++sl) {
        const int ch = ((t * 2 + sl) * 2 + hi) ^ xsw;   // k-chunk for this step
        short8 av0 = *(const short8*)&Vs0[cur * 4096 + (     l31) * 64 + (ch << 3)];
        short8 av1 = *(const short8*)&Vs0[cur * 4096 + (32 + l31) * 64 + (ch << 3)];
        h8 avh0, avh1;
        memcpy(&avh0, &av0, 16);
        memcpy(&avh1, &av1, 16);
        __builtin_amdgcn_s_setprio(1);
        #pragma unroll
        for (int qs = 0; qs < 2; ++qs) {
          u32 F0 = d[qs][4 * sl], F1 = d[qs][4 * sl + 1];
          u32 F2 = d[qs][4 * sl + 2], F3 = d[qs][4 * sl + 3];
          plswap(F0, F2);
          plswap(F1, F3);
          union { u32 w[4]; h8 v; } uf;
          uf.w[0] = F0; uf.w[1] = F1; uf.w[2] = F2; uf.w[3] = F3;
          accO[qs][0] = __builtin_amdgcn_mfma_f32_32x32x16_f16(avh0, uf.v, accO[qs][0], 0, 0, 0);
          accO[qs][1] = __builtin_amdgcn_mfma_f32_32x32x16_f16(avh1, uf.v, accO[qs][1], 0, 0, 0);
          accL[qs]    = __builtin_amdgcn_mfma_f32_32x32x16_f16(ones8, uf.v, accL[qs], 0, 0, 0);
        }
        __builtin_amdgcn_s_setprio(0);
      }
    }
  }

  // ---- combine: group 1 -> LDS scratch (dead Ks/Vs, 64KB) -> group 0 adds & stores ----
  __syncthreads();                         // all LDS reads of main loop done
  const int slot = wv * 64 + lane;         // 0..255 within group
  float* scr = (float*)smem;               // 16384 f32
  if (wg == 1) {
    #pragma unroll
    for (int qs = 0; qs < 2; ++qs)
      #pragma unroll
      for (int dt = 0; dt < 2; ++dt)
        #pragma unroll
        for (int rg = 0; rg < 4; ++rg) {
          const int c = (qs * 2 + dt) * 4 + rg;
          f32x4 v = {accO[qs][dt][4 * rg + 0], accO[qs][dt][4 * rg + 1],
                     accO[qs][dt][4 * rg + 2], accO[qs][dt][4 * rg + 3]};
          *(f32x4*)&scr[slot * 64 + ((c ^ (lane & 15)) << 2)] = v;
        }
    sL[0][slot] = accL[0][0];
    sL[1][slot] = accL[1][0];
  }
  __syncthreads();
  if (wg == 0) {
    #pragma unroll
    for (int qs = 0; qs < 2; ++qs) {
      const float inv = 1.0f / (accL[qs][0] + sL[qs][slot]);
      const int q = q0 + wv * 64 + qs * 32 + l31;
      #pragma unroll
      for (int dt = 0; dt < 2; ++dt)
        #pragma unroll
        for (int rg = 0; rg < 4; ++rg) {
          const int c = (qs * 2 + dt) * 4 + rg;
          f32x4 p = *(const f32x4*)&scr[slot * 64 + ((c ^ (lane & 15)) << 2)];
          ushort4 o = make_ushort4(f2b((accO[qs][dt][4 * rg + 0] + p[0]) * inv),
                                   f2b((accO[qs][dt][4 * rg + 1] + p[1]) * inv),
                                   f2b((accO[qs][dt][4 * rg + 2] + p[2]) * inv),
                                   f2b((accO[qs][dt][4 * rg + 3] + p[3]) * inv));
          *(ushort4*)&ctx[((size_t)b * 2048 + q) * 1024 + h * 64 + dt * 32 + rg * 8 + hi * 4] = o;
        }
    }
  }
}

// ---------- launch ----------
extern "C" void kernel_launch(void* const* d_in, const int* in_sizes, int n_in,
                              void* d_out, int out_size, void* d_ws, size_t ws_size,
                              hipStream_t stream) {
  const float* x          = (const float*)d_in[0];
  const float* Wq         = (const float*)d_in[1];
  const float* Wk         = (const float*)d_in[2];
  const float* Wv         = (const float*)d_in[3];
  const float* Wo         = (const float*)d_in[4];
  const float* bo         = (const float*)d_in[5];
  const float* bias_table = (const float*)d_in[6];
  float* out = (float*)d_out;

  char* ws = (char*)d_ws;
  u16* xb   = (u16*)(ws);                      // xb dead after QKV GEMM -> reused for gb4
  u16* wqb  = (u16*)(ws + 16777216);           // Wq,Wk,Wv,Wo bf16 contiguous
  u16* wob  = (u16*)(ws + 16777216 + 3 * 2097152);
  u16* qb   = (u16*)(ws + 25165824);           // q/k/v(t) contiguous, 16 MB each
  u16* kb   = qb + 8388608;
  u16* vtb  = kb + 8388608;                    // V stored [B,H,hd,S] as fp16
  u16* ctxb = (u16*)(ws + 75497472);
  f32x4* gb4 = (f32x4*)(ws);                   // 1MB, overlays dead xb

  cvt_f2b_kernel<<<8192, 256, 0, stream>>>(x, xb, 8388608);
  cvtw_kernel<<<dim3(1024, 4), 256, 0, stream>>>(Wq, Wk, Wv, Wo, wqb);

  gemm128_bt<0><<<dim3(64, 8, 3), 256, 0, stream>>>(
      xb, wqb, (void*)qb, nullptr, 8192, 1024, 1024);

  bias4x_kernel<<<256, 256, 0, stream>>>(bias_table, gb4);

  attn_mfma_kernel<<<dim3(64, 8), 512, 0, stream>>>(qb, kb, vtb, gb4, ctxb);

  gemm128_bt<1><<<dim3(64, 8), 256, 0, stream>>>(
      ctxb, wob, (void*)out, bo, 8192, 1024, 1024);
}

// Round 7
// 299.713 us; speedup vs baseline: 4.7553x; 4.7553x over previous
//
#include <hip/hip_runtime.h>
#include <string.h>

typedef unsigned short u16;
typedef unsigned int   u32;
typedef __attribute__((ext_vector_type(8))) short short8;     // 8 bf16/fp16 = 4 VGPRs
typedef __attribute__((ext_vector_type(4))) float f32x4;
typedef __attribute__((ext_vector_type(16))) float f32x16;
typedef __attribute__((ext_vector_type(2))) __fp16 h2;
typedef __attribute__((ext_vector_type(8))) __fp16 h8;
typedef __attribute__((ext_vector_type(2))) unsigned int u32x2;

// ---------- helpers ----------
__device__ __forceinline__ u16 f2b(float f) {                 // fp32 -> bf16 (RNE)
  u32 u = __float_as_uint(f);
  u32 r = (u + 0x7fffu + ((u >> 16) & 1u)) >> 16;
  return (u16)r;
}
// async global->LDS, 16B per lane; LDS dest = wave-uniform base + lane*16
__device__ __forceinline__ void cp16(const u16* g, u16* l) {
  __builtin_amdgcn_global_load_lds(
      (const __attribute__((address_space(1))) void*)g,
      (__attribute__((address_space(3))) void*)l, 16, 0, 0);
}
// v_permlane32_swap: a' = {a.lo32 | b.lo32}, b' = {a.hi32 | b.hi32}
__device__ __forceinline__ void plswap(u32& a, u32& b) {
  u32x2 r = __builtin_amdgcn_permlane32_swap(a, b, false, false);
  a = r[0]; b = r[1];
}

// ---------- fp32 -> bf16 conversion ----------
__global__ __launch_bounds__(256) void cvt_f2b_kernel(const float* __restrict__ in,
                                                      u16* __restrict__ out, int n) {
  int i = (blockIdx.x * 256 + threadIdx.x) * 4;
  if (i + 3 < n) {
    float4 v = *(const float4*)&in[i];
    ushort4 o = make_ushort4(f2b(v.x), f2b(v.y), f2b(v.z), f2b(v.w));
    *(ushort4*)&out[i] = o;
  }
}
// 4 weight matrices in one launch (blockIdx.y selects)
__global__ __launch_bounds__(256) void cvtw_kernel(const float* __restrict__ w0,
                                                   const float* __restrict__ w1,
                                                   const float* __restrict__ w2,
                                                   const float* __restrict__ w3,
                                                   u16* __restrict__ out) {
  const float* src = (blockIdx.y == 0) ? w0 : (blockIdx.y == 1) ? w1
                   : (blockIdx.y == 2) ? w2 : w3;
  int i = (blockIdx.x * 256 + threadIdx.x) * 4;
  float4 v = *(const float4*)&src[i];
  ushort4 o = make_ushort4(f2b(v.x), f2b(v.y), f2b(v.z), f2b(v.w));
  *(ushort4*)&out[(size_t)blockIdx.y * 1048576 + i] = o;
}

// ---------- bias4 expansion: gb4[h][j] = {bt[j-3..j]} * log2(e), clamped ----------
__global__ __launch_bounds__(256) void bias4x_kernel(const float* __restrict__ bt,
                                                     f32x4* __restrict__ gb4) {
  int idx = blockIdx.x * 256 + threadIdx.x;   // grid 256 -> 65536 = 16 heads x 4096
  int h = idx >> 12, j = idx & 4095;
  f32x4 v;
  #pragma unroll
  for (int e = 0; e < 4; ++e) {
    int r = j - 3 + e;
    r = r < 0 ? 0 : (r > 4094 ? 4094 : r);
    v[e] = bt[r * 16 + h] * 1.44269504f;
  }
  gb4[idx] = v;
}

// ---------- bf16 MFMA GEMM, BK=32, single-barrier dbuf pipeline (r3 version) ----------
template<int MODE>
__global__ __launch_bounds__(256) void gemm128_bt(
    const u16* __restrict__ A, const u16* __restrict__ Bw,
    void* __restrict__ outp, const float* __restrict__ bias,
    const int M, const int N, const int K) {
  __shared__ __attribute__((aligned(16))) u16 As[2][128 * 32];
  __shared__ __attribute__((aligned(16))) u16 Bs[2][128 * 32];

  const u16* Bw2 = Bw;
  if (MODE == 0) Bw2 += ((size_t)blockIdx.z) << 20;

  const int tid  = threadIdx.x;
  const int wave = tid >> 6, lane = tid & 63;
  const int quad = lane >> 4, l15 = lane & 15;
  const int wm   = (wave >> 1) * 64, wn = (wave & 1) * 64;
  const int m0   = blockIdx.x * 128, n0 = blockIdx.y * 128;

  const int srow = wave * 32 + (lane >> 2);
  const int scol = (lane & 3) * 8;
  const u16* gA0 = A   + (size_t)(m0 + srow) * K + scol;
  const u16* gA1 = gA0 + (size_t)16 * K;
  const u16* gB0 = Bw2 + (size_t)(n0 + srow) * K + scol;
  const u16* gB1 = gB0 + (size_t)16 * K;
  const int lo0 = (wave * 32) * 32, lo1 = (wave * 32 + 16) * 32;

  cp16(gA0, &As[0][lo0]); cp16(gA1, &As[0][lo1]);
  cp16(gB0, &Bs[0][lo0]); cp16(gB1, &Bs[0][lo1]);
  gA0 += 32; gA1 += 32; gB0 += 32; gB1 += 32;

  f32x4 acc[4][4] = {};
  const int nk = K >> 5;
  for (int kt = 0; kt < nk; ++kt) {
    const int cur = kt & 1;
    __syncthreads();
    if (kt + 1 < nk) {
      cp16(gA0, &As[1 - cur][lo0]); cp16(gA1, &As[1 - cur][lo1]);
      cp16(gB0, &Bs[1 - cur][lo0]); cp16(gB1, &Bs[1 - cur][lo1]);
      gA0 += 32; gA1 += 32; gB0 += 32; gB1 += 32;
    }
    short8 af[4], bf[4];
    #pragma unroll
    for (int mi = 0; mi < 4; ++mi)
      af[mi] = *(const short8*)&As[cur][(wm + mi * 16 + l15) * 32 + quad * 8];
    #pragma unroll
    for (int ni = 0; ni < 4; ++ni)
      bf[ni] = *(const short8*)&Bs[cur][(wn + ni * 16 + l15) * 32 + quad * 8];
    #pragma unroll
    for (int mi = 0; mi < 4; ++mi)
      #pragma unroll
      for (int ni = 0; ni < 4; ++ni)
        acc[mi][ni] = __builtin_amdgcn_mfma_f32_16x16x32_bf16(af[mi], bf[ni], acc[mi][ni], 0, 0, 0);
  }

  #pragma unroll
  for (int mi = 0; mi < 4; ++mi)
    #pragma unroll
    for (int ni = 0; ni < 4; ++ni) {
      if (MODE == 0 && blockIdx.z == 2) {
        int mb = m0 + wm + mi * 16 + quad * 4;
        int n  = n0 + wn + ni * 16 + l15;
        int b = mb >> 11, s = mb & 2047, h = n >> 6, d = n & 63;
        u16* out = (u16*)outp + (((size_t)2) << 23);
        h2 p0 = __builtin_amdgcn_cvt_pkrtz(acc[mi][ni][0], acc[mi][ni][1]);
        h2 p1 = __builtin_amdgcn_cvt_pkrtz(acc[mi][ni][2], acc[mi][ni][3]);
        ushort4 o;
        memcpy(&o.x, &p0, 4);
        memcpy(&o.z, &p1, 4);
        *(ushort4*)&out[((((size_t)b * 16 + h) * 64 + d) << 11) + s] = o;
      } else {
        #pragma unroll
        for (int r = 0; r < 4; ++r) {
          int m = m0 + wm + mi * 16 + quad * 4 + r;
          int n = n0 + wn + ni * 16 + l15;
          float v = acc[mi][ni][r];
          if (MODE == 0) {
            int b = m >> 11, s = m & 2047, h = n >> 6, d = n & 63;
            u16* out = (u16*)outp + (((size_t)blockIdx.z) << 23);
            out[((((size_t)b * 16 + h) * 2048 + s) << 6) + d] = f2b(v);
          } else {
            ((float*)outp)[(size_t)m * N + n] = v + bias[n];
          }
        }
      }
    }
}

// ---------- MFMA flash attention, 32x32x16, split-K, REDUCED STATE ----------
// r7 = r6 with the spill fixed:
//  - __launch_bounds__(512, 2): hipcc's 2nd arg behaves CUDA-style (min BLOCKS/CU):
//    r6's (512,4) demanded 8 waves/SIMD -> VGPR cap 64 -> catastrophic scratch spill
//    (FETCH 2.2GB). (512,2) = 16 waves/CU = 4/SIMD -> cap 128.
//  - 32 q/wave (accO 32 regs, aQ 16), scalar f32 lsum (no accL MFMA): peak live ~110.
// 512 threads = 2 k-groups x 4 q-waves; block covers 128 q; grid (64, 16).
__global__ __launch_bounds__(512, 2) void attn_mfma_kernel(
    const u16* __restrict__ qb, const u16* __restrict__ kb, const u16* __restrict__ vtb,
    const f32x4* __restrict__ gb4, u16* __restrict__ ctx) {
  __shared__ __attribute__((aligned(16))) u16 smem[32768];   // 64KB: Ks[g][buf] + Vs[g][buf]
  __shared__ float sL[256];

  const int tid  = threadIdx.x;
  const int wave = tid >> 6, lane = tid & 63;
  const int wg   = wave >> 2, wv = wave & 3;   // k-group, q-wave
  const int l31  = lane & 31, hi = lane >> 5;
  const int xsw  = l31 & 7;
  const int bh   = blockIdx.x, h = bh & 15, b = bh >> 4;
  const int q0   = blockIdx.y * 128;

  u16* Ks0 = smem + (wg * 2) * 4096;            // + buf*4096
  u16* Vs0 = smem + 16384 + (wg * 2) * 4096;    // + buf*4096

  // Q B-frags: n = q = wv*32+l31, k(=d) = ks*16 + hi*8 + j
  short8 aQ[4];
  #pragma unroll
  for (int ks = 0; ks < 4; ++ks)
    aQ[ks] = *(const short8*)&qb[((size_t)bh * 2048 + q0 + wv * 32 + l31) * 64
                                 + ks * 16 + hi * 8];

  f32x16 accO[2] = {};   // [dt]; row d = (r&3)+8*(r>>2)+4*hi+32*dt, col q = l31
  float  lsum = 0.f;

  // K staging (global_load_lds, pre-swizzled global source); group row offset wg*1024
  const int krow = lane >> 3;
  const int kchk = (lane & 7) ^ krow;
  const u16* kbase = kb + (((size_t)bh * 2048 + (wg << 10)) << 6);

  // V staging via regs -> swizzled LDS writes (per-group 256 threads)
  const int tg = tid & 255;
  const int srow = tg >> 2, t0 = tg & 3, ssw = srow & 7;
  const u16* vrow = vtb + (((size_t)bh * 64 + srow) << 11) + (wg << 10) + t0 * 16;
  const int vo0 = srow * 64 + (((2 * t0    ) ^ ssw) << 3);
  const int vo1 = srow * 64 + (((2 * t0 + 1) ^ ssw) << 3);

  const f32x4* gb = gb4 + (h << 12);

  // prologue: stage tile 0, prefetch tile 1 regs
  short8 vpre0 = *(const short8*)&vrow[0];
  short8 vpre1 = *(const short8*)&vrow[8];
  *(short8*)&Vs0[vo0] = vpre0;           // compiler inserts vmcnt wait
  *(short8*)&Vs0[vo1] = vpre1;
  #pragma unroll
  for (int g = 0; g < 2; ++g)
    cp16(kbase + (size_t)(wv * 16 + g * 8 + krow) * 64 + kchk * 8,
         &Ks0[(wv * 16 + g * 8) * 64]);
  vpre0 = *(const short8*)&vrow[64];
  vpre1 = *(const short8*)&vrow[72];

  for (int kt = 0; kt < 16; ++kt) {
    const int cur = kt & 1;
    __syncthreads();   // drains cp16(kt) + vpre loads; makes Vs[cur] writes visible
    if (kt < 15) {
      #pragma unroll
      for (int g = 0; g < 2; ++g)
        cp16(kbase + (size_t)((kt + 1) * 64 + wv * 16 + g * 8 + krow) * 64 + kchk * 8,
             &Ks0[(1 - cur) * 4096 + (wv * 16 + g * 8) * 64]);
      *(short8*)&Vs0[(1 - cur) * 4096 + vo0] = vpre0;   // V(kt+1), already landed
      *(short8*)&Vs0[(1 - cur) * 4096 + vo1] = vpre1;
      if (kt < 14) {
        const u16* vp = vrow + ((size_t)(kt + 2) << 6);
        vpre0 = *(const short8*)&vp[0];
        vpre1 = *(const short8*)&vp[8];
      }
    }

    #pragma unroll
    for (int t = 0; t < 2; ++t) {
      // ---- S^T tile t: rows k = t*32 + row(r,hi), cols q ----
      short8 aK[4];
      #pragma unroll
      for (int ks = 0; ks < 4; ++ks)
        aK[ks] = *(const short8*)&Ks0[cur * 4096 + (t * 32 + l31) * 64
                                      + (((ks * 2 + hi) ^ xsw) << 3)];
      f32x16 accS = {};
      __builtin_amdgcn_s_setprio(1);
      #pragma unroll
      for (int ks = 0; ks < 4; ++ks)
        accS = __builtin_amdgcn_mfma_f32_32x32x16_bf16(aK[ks], aQ[ks], accS, 0, 0, 0);
      __builtin_amdgcn_s_setprio(0);

      // ---- softmax: p = exp2(S*log2e/8 + bias*log2e); one global b128 bias read/rg ----
      // accS elem r=4rg+j sits at k-row (j + 8rg + 4hi); needed bt index = q-k+2047.
      // gb4[J] = {bt[J-3..J]}, usage bb4[3-j] -> J = base - 8rg, base ends +2047.
      u32 d[8];
      const int ibJ = q0 + wv * 32 + l31 - (wg << 10) - kt * 64 - t * 32 - 4 * hi + 2047;
      #pragma unroll
      for (int rg = 0; rg < 4; ++rg) {
        const f32x4 bb4 = gb[ibJ - 8 * rg];   // [0]=bt(J-3) .. [3]=bt(J)
        float p0 = __builtin_amdgcn_exp2f(fmaf(accS[4 * rg + 0], 0.18033688f, bb4[3]));
        float p1 = __builtin_amdgcn_exp2f(fmaf(accS[4 * rg + 1], 0.18033688f, bb4[2]));
        float p2 = __builtin_amdgcn_exp2f(fmaf(accS[4 * rg + 2], 0.18033688f, bb4[1]));
        float p3 = __builtin_amdgcn_exp2f(fmaf(accS[4 * rg + 3], 0.18033688f, bb4[0]));
        lsum += (p0 + p1) + (p2 + p3);
        h2 e0; e0[0] = (__fp16)p0; e0[1] = (__fp16)p1;
        h2 e1; e1[0] = (__fp16)p2; e1[1] = (__fp16)p3;
        memcpy(&d[2 * rg],     &e0, 4);
        memcpy(&d[2 * rg + 1], &e1, 4);
      }

      // ---- PV: redistribute P (permlane32) and accumulate O^T ----
      #pragma unroll
      for (int sl = 0; sl < 2; ++sl) {
        const int ch = ((t * 2 + sl) * 2 + hi) ^ xsw;   // k-chunk for this step
        short8 av0 = *(const short8*)&Vs0[cur * 4096 + (     l31) * 64 + (ch << 3)];
        short8 av1 = *(const short8*)&Vs0[cur * 4096 + (32 + l31) * 64 + (ch << 3)];
        h8 avh0, avh1;
        memcpy(&avh0, &av0, 16);
        memcpy(&avh1, &av1, 16);
        u32 F0 = d[4 * sl], F1 = d[4 * sl + 1];
        u32 F2 = d[4 * sl + 2], F3 = d[4 * sl + 3];
        plswap(F0, F2);
        plswap(F1, F3);
        union { u32 w[4]; h8 v; } uf;
        uf.w[0] = F0; uf.w[1] = F1; uf.w[2] = F2; uf.w[3] = F3;
        __builtin_amdgcn_s_setprio(1);
        accO[0] = __builtin_amdgcn_mfma_f32_32x32x16_f16(avh0, uf.v, accO[0], 0, 0, 0);
        accO[1] = __builtin_amdgcn_mfma_f32_32x32x16_f16(avh1, uf.v, accO[1], 0, 0, 0);
        __builtin_amdgcn_s_setprio(0);
      }
    }
  }

  // ---- combine: group 1 -> LDS scratch (dead Ks/Vs) -> group 0 adds & stores ----
  __syncthreads();                         // all LDS reads of main loop done
  const int slot = wv * 64 + lane;         // 0..255 within group
  float* scr = (float*)smem;               // 8192 f32 = 32KB
  const float lg = lsum + __shfl_xor(lsum, 32);   // full column sum for this group
  if (wg == 1) {
    #pragma unroll
    for (int dt = 0; dt < 2; ++dt)
      #pragma unroll
      for (int rg = 0; rg < 4; ++rg) {
        const int c = dt * 4 + rg;
        f32x4 v = {accO[dt][4 * rg + 0], accO[dt][4 * rg + 1],
                   accO[dt][4 * rg + 2], accO[dt][4 * rg + 3]};
        *(f32x4*)&scr[slot * 32 + ((c ^ (lane & 7)) << 2)] = v;
      }
    sL[slot] = lg;
  }
  __syncthreads();
  if (wg == 0) {
    const float inv = 1.0f / (lg + sL[slot]);
    const int q = q0 + wv * 32 + l31;
    #pragma unroll
    for (int dt = 0; dt < 2; ++dt)
      #pragma unroll
      for (int rg = 0; rg < 4; ++rg) {
        const int c = dt * 4 + rg;
        f32x4 p = *(const f32x4*)&scr[slot * 32 + ((c ^ (lane & 7)) << 2)];
        ushort4 o = make_ushort4(f2b((accO[dt][4 * rg + 0] + p[0]) * inv),
                                 f2b((accO[dt][4 * rg + 1] + p[1]) * inv),
                                 f2b((accO[dt][4 * rg + 2] + p[2]) * inv),
                                 f2b((accO[dt][4 * rg + 3] + p[3]) * inv));
        *(ushort4*)&ctx[((size_t)b * 2048 + q) * 1024 + h * 64 + dt * 32 + rg * 8 + hi * 4] = o;
      }
  }
}

// ---------- launch ----------
extern "C" void kernel_launch(void* const* d_in, const int* in_sizes, int n_in,
                              void* d_out, int out_size, void* d_ws, size_t ws_size,
                              hipStream_t stream) {
  const float* x          = (const float*)d_in[0];
  const float* Wq         = (const float*)d_in[1];
  const float* Wk         = (const float*)d_in[2];
  const float* Wv         = (const float*)d_in[3];
  const float* Wo         = (const float*)d_in[4];
  const float* bo         = (const float*)d_in[5];
  const float* bias_table = (const float*)d_in[6];
  float* out = (float*)d_out;

  char* ws = (char*)d_ws;
  u16* xb   = (u16*)(ws);                      // xb dead after QKV GEMM -> reused for gb4
  u16* wqb  = (u16*)(ws + 16777216);           // Wq,Wk,Wv,Wo bf16 contiguous
  u16* wob  = (u16*)(ws + 16777216 + 3 * 2097152);
  u16* qb   = (u16*)(ws + 25165824);           // q/k/v(t) contiguous, 16 MB each
  u16* kb   = qb + 8388608;
  u16* vtb  = kb + 8388608;                    // V stored [B,H,hd,S] as fp16
  u16* ctxb = (u16*)(ws + 75497472);
  f32x4* gb4 = (f32x4*)(ws);                   // 1MB, overlays dead xb

  cvt_f2b_kernel<<<8192, 256, 0, stream>>>(x, xb, 8388608);
  cvtw_kernel<<<dim3(1024, 4), 256, 0, stream>>>(Wq, Wk, Wv, Wo, wqb);

  gemm128_bt<0><<<dim3(64, 8, 3), 256, 0, stream>>>(
      xb, wqb, (void*)qb, nullptr, 8192, 1024, 1024);

  bias4x_kernel<<<256, 256, 0, stream>>>(bias_table, gb4);

  attn_mfma_kernel<<<dim3(64, 16), 512, 0, stream>>>(qb, kb, vtb, gb4, ctxb);

  gemm128_bt<1><<<dim3(64, 8), 256, 0, stream>>>(
      ctxb, wob, (void*)out, bo, 8192, 1024, 1024);
}

// Round 8
// 291.053 us; speedup vs baseline: 4.8968x; 1.0298x over previous
//
#include <hip/hip_runtime.h>
#include <string.h>

typedef unsigned short u16;
typedef unsigned int   u32;
typedef __attribute__((ext_vector_type(8))) short short8;     // 8 bf16/fp16 = 4 VGPRs
typedef __attribute__((ext_vector_type(4))) float f32x4;
typedef __attribute__((ext_vector_type(16))) float f32x16;
typedef __attribute__((ext_vector_type(2))) __fp16 h2;
typedef __attribute__((ext_vector_type(8))) __fp16 h8;
typedef __attribute__((ext_vector_type(2))) unsigned int u32x2;

// ---------- helpers ----------
__device__ __forceinline__ u16 f2b(float f) {                 // fp32 -> bf16 (RNE)
  u32 u = __float_as_uint(f);
  u32 r = (u + 0x7fffu + ((u >> 16) & 1u)) >> 16;
  return (u16)r;
}
// async global->LDS, 16B per lane; LDS dest = wave-uniform base + lane*16
__device__ __forceinline__ void cp16(const u16* g, u16* l) {
  __builtin_amdgcn_global_load_lds(
      (const __attribute__((address_space(1))) void*)g,
      (__attribute__((address_space(3))) void*)l, 16, 0, 0);
}
// v_permlane32_swap: a' = {a.lo32 | b.lo32}, b' = {a.hi32 | b.hi32}
__device__ __forceinline__ void plswap(u32& a, u32& b) {
  u32x2 r = __builtin_amdgcn_permlane32_swap(a, b, false, false);
  a = r[0]; b = r[1];
}

// ---------- fp32 -> bf16 conversion ----------
__global__ __launch_bounds__(256) void cvt_f2b_kernel(const float* __restrict__ in,
                                                      u16* __restrict__ out, int n) {
  int i = (blockIdx.x * 256 + threadIdx.x) * 4;
  if (i + 3 < n) {
    float4 v = *(const float4*)&in[i];
    ushort4 o = make_ushort4(f2b(v.x), f2b(v.y), f2b(v.z), f2b(v.w));
    *(ushort4*)&out[i] = o;
  }
}
// 4 weight matrices in one launch (blockIdx.y selects)
__global__ __launch_bounds__(256) void cvtw_kernel(const float* __restrict__ w0,
                                                   const float* __restrict__ w1,
                                                   const float* __restrict__ w2,
                                                   const float* __restrict__ w3,
                                                   u16* __restrict__ out) {
  const float* src = (blockIdx.y == 0) ? w0 : (blockIdx.y == 1) ? w1
                   : (blockIdx.y == 2) ? w2 : w3;
  int i = (blockIdx.x * 256 + threadIdx.x) * 4;
  float4 v = *(const float4*)&src[i];
  ushort4 o = make_ushort4(f2b(v.x), f2b(v.y), f2b(v.z), f2b(v.w));
  *(ushort4*)&out[(size_t)blockIdx.y * 1048576 + i] = o;
}

// ---------- bias4 expansion: gb4[h][j] = {bt[j-3..j]} * log2(e), clamped ----------
__global__ __launch_bounds__(256) void bias4x_kernel(const float* __restrict__ bt,
                                                     f32x4* __restrict__ gb4) {
  int idx = blockIdx.x * 256 + threadIdx.x;   // grid 256 -> 65536 = 16 heads x 4096
  int h = idx >> 12, j = idx & 4095;
  f32x4 v;
  #pragma unroll
  for (int e = 0; e < 4; ++e) {
    int r = j - 3 + e;
    r = r < 0 ? 0 : (r > 4094 ? 4094 : r);
    v[e] = bt[r * 16 + h] * 1.44269504f;
  }
  gb4[idx] = v;
}

// ---------- bf16 MFMA GEMM, BK=32, single-barrier dbuf pipeline (r3 version) ----------
template<int MODE>
__global__ __launch_bounds__(256) void gemm128_bt(
    const u16* __restrict__ A, const u16* __restrict__ Bw,
    void* __restrict__ outp, const float* __restrict__ bias,
    const int M, const int N, const int K) {
  __shared__ __attribute__((aligned(16))) u16 As[2][128 * 32];
  __shared__ __attribute__((aligned(16))) u16 Bs[2][128 * 32];

  const u16* Bw2 = Bw;
  if (MODE == 0) Bw2 += ((size_t)blockIdx.z) << 20;

  const int tid  = threadIdx.x;
  const int wave = tid >> 6, lane = tid & 63;
  const int quad = lane >> 4, l15 = lane & 15;
  const int wm   = (wave >> 1) * 64, wn = (wave & 1) * 64;
  const int m0   = blockIdx.x * 128, n0 = blockIdx.y * 128;

  const int srow = wave * 32 + (lane >> 2);
  const int scol = (lane & 3) * 8;
  const u16* gA0 = A   + (size_t)(m0 + srow) * K + scol;
  const u16* gA1 = gA0 + (size_t)16 * K;
  const u16* gB0 = Bw2 + (size_t)(n0 + srow) * K + scol;
  const u16* gB1 = gB0 + (size_t)16 * K;
  const int lo0 = (wave * 32) * 32, lo1 = (wave * 32 + 16) * 32;

  cp16(gA0, &As[0][lo0]); cp16(gA1, &As[0][lo1]);
  cp16(gB0, &Bs[0][lo0]); cp16(gB1, &Bs[0][lo1]);
  gA0 += 32; gA1 += 32; gB0 += 32; gB1 += 32;

  f32x4 acc[4][4] = {};
  const int nk = K >> 5;
  for (int kt = 0; kt < nk; ++kt) {
    const int cur = kt & 1;
    __syncthreads();
    if (kt + 1 < nk) {
      cp16(gA0, &As[1 - cur][lo0]); cp16(gA1, &As[1 - cur][lo1]);
      cp16(gB0, &Bs[1 - cur][lo0]); cp16(gB1, &Bs[1 - cur][lo1]);
      gA0 += 32; gA1 += 32; gB0 += 32; gB1 += 32;
    }
    short8 af[4], bf[4];
    #pragma unroll
    for (int mi = 0; mi < 4; ++mi)
      af[mi] = *(const short8*)&As[cur][(wm + mi * 16 + l15) * 32 + quad * 8];
    #pragma unroll
    for (int ni = 0; ni < 4; ++ni)
      bf[ni] = *(const short8*)&Bs[cur][(wn + ni * 16 + l15) * 32 + quad * 8];
    #pragma unroll
    for (int mi = 0; mi < 4; ++mi)
      #pragma unroll
      for (int ni = 0; ni < 4; ++ni)
        acc[mi][ni] = __builtin_amdgcn_mfma_f32_16x16x32_bf16(af[mi], bf[ni], acc[mi][ni], 0, 0, 0);
  }

  #pragma unroll
  for (int mi = 0; mi < 4; ++mi)
    #pragma unroll
    for (int ni = 0; ni < 4; ++ni) {
      if (MODE == 0 && blockIdx.z == 2) {
        int mb = m0 + wm + mi * 16 + quad * 4;
        int n  = n0 + wn + ni * 16 + l15;
        int b = mb >> 11, s = mb & 2047, h = n >> 6, d = n & 63;
        u16* out = (u16*)outp + (((size_t)2) << 23);
        h2 p0 = __builtin_amdgcn_cvt_pkrtz(acc[mi][ni][0], acc[mi][ni][1]);
        h2 p1 = __builtin_amdgcn_cvt_pkrtz(acc[mi][ni][2], acc[mi][ni][3]);
        ushort4 o;
        memcpy(&o.x, &p0, 4);
        memcpy(&o.z, &p1, 4);
        *(ushort4*)&out[((((size_t)b * 16 + h) * 64 + d) << 11) + s] = o;
      } else {
        #pragma unroll
        for (int r = 0; r < 4; ++r) {
          int m = m0 + wm + mi * 16 + quad * 4 + r;
          int n = n0 + wn + ni * 16 + l15;
          float v = acc[mi][ni][r];
          if (MODE == 0) {
            int b = m >> 11, s = m & 2047, h = n >> 6, d = n & 63;
            u16* out = (u16*)outp + (((size_t)blockIdx.z) << 23);
            out[((((size_t)b * 16 + h) * 2048 + s) << 6) + d] = f2b(v);
          } else {
            ((float*)outp)[(size_t)m * N + n] = v + bias[n];
          }
        }
      }
    }
}

// ---------- MFMA flash attention: r3 structure + GLOBAL bias table ----------
// r8 = exact r3 kernel (best measured: 100.0 us) with bias4 moved from LDS to the
// precomputed global gb4 table (indexing validated in r7 with the +2047 base).
// Removes 16 of 26 LDS ops/wave-iter + the build prologue; LDS 69.6KB -> 33KB.
// 4 waves x 64 q/wave, 2 k-tiles buffered, 1 barrier/iter, grid (64,8).
__global__ __launch_bounds__(256, 2) void attn_mfma_kernel(
    const u16* __restrict__ qb, const u16* __restrict__ kb, const u16* __restrict__ vtb,
    const f32x4* __restrict__ gb4, u16* __restrict__ ctx) {
  __shared__ __attribute__((aligned(16))) u16 Ks[2][64 * 64];  // dbuf, XOR-swizzled
  __shared__ __attribute__((aligned(16))) u16 Vs[2][64 * 64];  // dbuf, [d][k] fp16, XOR-swizzled

  const int tid  = threadIdx.x;
  const int wave = tid >> 6, lane = tid & 63;
  const int l31  = lane & 31, hi = lane >> 5;
  const int xsw  = l31 & 7;
  const int bh   = blockIdx.x, h = bh & 15, b = bh >> 4;
  const int q0   = blockIdx.y * 256;

  // Q B-frags: n = q, k(=d) = ks*16 + hi*8 + j
  short8 aQ[2][4];
  #pragma unroll
  for (int qs = 0; qs < 2; ++qs)
    #pragma unroll
    for (int ks = 0; ks < 4; ++ks)
      aQ[qs][ks] = *(const short8*)&qb[((size_t)bh * 2048 + q0 + wave * 64 + qs * 32 + l31) * 64
                                       + ks * 16 + hi * 8];

  f32x16 accO[2][2] = {};   // [qs][dt]; row d = (r&3)+8*(r>>2)+4*hi+32*dt, col q = l31
  f32x16 accL[2]    = {};   // lsum via ones-MFMA; accL[qs][0] = full k-sum for col q

  const h8 ones8 = {(__fp16)1.f, (__fp16)1.f, (__fp16)1.f, (__fp16)1.f,
                    (__fp16)1.f, (__fp16)1.f, (__fp16)1.f, (__fp16)1.f};

  // K staging (global_load_lds, pre-swizzled global source)
  const int krow = lane >> 3;
  const int kchk = (lane & 7) ^ krow;
  const u16* kbase = kb + (((size_t)bh * 2048) << 6);

  // V staging via regs -> swizzled LDS writes
  const int srow = tid >> 2, t0 = tid & 3, ssw = srow & 7;
  const u16* vrow = vtb + (((size_t)bh * 64 + srow) << 11) + t0 * 16;
  const int vo0 = srow * 64 + (((2 * t0    ) ^ ssw) << 3);
  const int vo1 = srow * 64 + (((2 * t0 + 1) ^ ssw) << 3);

  const f32x4* gb = gb4 + (h << 12);

  // prologue: stage tile 0, prefetch tile 1 regs
  short8 vpre0 = *(const short8*)&vrow[0];
  short8 vpre1 = *(const short8*)&vrow[8];
  *(short8*)&Vs[0][vo0] = vpre0;           // compiler inserts vmcnt wait
  *(short8*)&Vs[0][vo1] = vpre1;
  #pragma unroll
  for (int g = 0; g < 2; ++g)
    cp16(kbase + (size_t)(wave * 16 + g * 8 + krow) * 64 + kchk * 8,
         &Ks[0][(wave * 16 + g * 8) * 64]);
  vpre0 = *(const short8*)&vrow[64];
  vpre1 = *(const short8*)&vrow[72];

  for (int kt = 0; kt < 32; ++kt) {
    const int cur = kt & 1;
    __syncthreads();   // drains cp16(kt) + vpre loads; makes Vs[cur] writes visible
    if (kt < 31) {
      #pragma unroll
      for (int g = 0; g < 2; ++g)
        cp16(kbase + (size_t)((kt + 1) * 64 + wave * 16 + g * 8 + krow) * 64 + kchk * 8,
             &Ks[1 - cur][(wave * 16 + g * 8) * 64]);
      *(short8*)&Vs[1 - cur][vo0] = vpre0;   // V(kt+1), already landed (drained at barrier)
      *(short8*)&Vs[1 - cur][vo1] = vpre1;
      if (kt < 30) {
        const u16* vp = vrow + ((size_t)(kt + 2) << 6);
        vpre0 = *(const short8*)&vp[0];
        vpre1 = *(const short8*)&vp[8];
      }
    }

    #pragma unroll
    for (int t = 0; t < 2; ++t) {
      // ---- S^T tile t: rows k = t*32 + row(r,hi), cols q; aK shared across qs ----
      short8 aK[4];
      #pragma unroll
      for (int ks = 0; ks < 4; ++ks)
        aK[ks] = *(const short8*)&Ks[cur][(t * 32 + l31) * 64
                                          + (((ks * 2 + hi) ^ xsw) << 3)];
      f32x16 accS[2] = {};
      __builtin_amdgcn_s_setprio(1);
      #pragma unroll
      for (int ks = 0; ks < 4; ++ks)
        #pragma unroll
        for (int qs = 0; qs < 2; ++qs)
          accS[qs] = __builtin_amdgcn_mfma_f32_32x32x16_bf16(aK[ks], aQ[qs][ks], accS[qs], 0, 0, 0);
      __builtin_amdgcn_s_setprio(0);

      // ---- softmax: p = exp2(S*log2e/8 + bias*log2e); one global b128 bias read/rg ----
      // accS elem r=4rg+j sits at k-row (j + 8rg + 4hi + t*32 + kt*64); needed
      // bt index = q-k+2047. gb4[J] = {bt[J-3..J]}, use bb4[3-j] with
      // J = q0+wave*64+qs*32+l31 - kt*64 - t*32 - 4hi + 2047 - 8rg  (range [3,4094]).
      u32 d[2][8];
      #pragma unroll
      for (int qs = 0; qs < 2; ++qs) {
        const int ibJ = q0 + wave * 64 + qs * 32 + l31 - kt * 64 - t * 32 - 4 * hi + 2047;
        #pragma unroll
        for (int rg = 0; rg < 4; ++rg) {
          const f32x4 bb4 = gb[ibJ - 8 * rg];   // [0]=bt(J-3) .. [3]=bt(J)
          float p0 = __builtin_amdgcn_exp2f(fmaf(accS[qs][4 * rg + 0], 0.18033688f, bb4[3]));
          float p1 = __builtin_amdgcn_exp2f(fmaf(accS[qs][4 * rg + 1], 0.18033688f, bb4[2]));
          float p2 = __builtin_amdgcn_exp2f(fmaf(accS[qs][4 * rg + 2], 0.18033688f, bb4[1]));
          float p3 = __builtin_amdgcn_exp2f(fmaf(accS[qs][4 * rg + 3], 0.18033688f, bb4[0]));
          h2 e0; e0[0] = (__fp16)p0; e0[1] = (__fp16)p1;
          h2 e1; e1[0] = (__fp16)p2; e1[1] = (__fp16)p3;
          memcpy(&d[qs][2 * rg],     &e0, 4);
          memcpy(&d[qs][2 * rg + 1], &e1, 4);
        }
      }

      // ---- PV + lsum: V reads shared across qs; lsum on MFMA pipe ----
      #pragma unroll
      for (int sl = 0; sl < 2; ++sl) {
        const int ch = ((t * 2 + sl) * 2 + hi) ^ xsw;   // k-chunk for this step
        short8 av0 = *(const short8*)&Vs[cur][(     l31) * 64 + (ch << 3)];
        short8 av1 = *(const short8*)&Vs[cur][(32 + l31) * 64 + (ch << 3)];
        h8 avh0, avh1;
        memcpy(&avh0, &av0, 16);
        memcpy(&avh1, &av1, 16);
        __builtin_amdgcn_s_setprio(1);
        #pragma unroll
        for (int qs = 0; qs < 2; ++qs) {
          u32 F0 = d[qs][4 * sl], F1 = d[qs][4 * sl + 1];
          u32 F2 = d[qs][4 * sl + 2], F3 = d[qs][4 * sl + 3];
          plswap(F0, F2);
          plswap(F1, F3);
          union { u32 w[4]; h8 v; } uf;
          uf.w[0] = F0; uf.w[1] = F1; uf.w[2] = F2; uf.w[3] = F3;
          accO[qs][0] = __builtin_amdgcn_mfma_f32_32x32x16_f16(avh0, uf.v, accO[qs][0], 0, 0, 0);
          accO[qs][1] = __builtin_amdgcn_mfma_f32_32x32x16_f16(avh1, uf.v, accO[qs][1], 0, 0, 0);
          accL[qs]    = __builtin_amdgcn_mfma_f32_32x32x16_f16(ones8, uf.v, accL[qs], 0, 0, 0);
        }
        __builtin_amdgcn_s_setprio(0);
      }
    }
  }

  // ---- epilogue: accL[qs][0] already holds the full k-sum for col q ----
  #pragma unroll
  for (int qs = 0; qs < 2; ++qs) {
    const float inv = 1.0f / accL[qs][0];
    const int q = q0 + wave * 64 + qs * 32 + l31;
    #pragma unroll
    for (int dt = 0; dt < 2; ++dt)
      #pragma unroll
      for (int rg = 0; rg < 4; ++rg) {
        ushort4 o = make_ushort4(f2b(accO[qs][dt][4 * rg + 0] * inv), f2b(accO[qs][dt][4 * rg + 1] * inv),
                                 f2b(accO[qs][dt][4 * rg + 2] * inv), f2b(accO[qs][dt][4 * rg + 3] * inv));
        *(ushort4*)&ctx[((size_t)b * 2048 + q) * 1024 + h * 64 + dt * 32 + rg * 8 + hi * 4] = o;
      }
  }
}

// ---------- launch ----------
extern "C" void kernel_launch(void* const* d_in, const int* in_sizes, int n_in,
                              void* d_out, int out_size, void* d_ws, size_t ws_size,
                              hipStream_t stream) {
  const float* x          = (const float*)d_in[0];
  const float* Wq         = (const float*)d_in[1];
  const float* Wk         = (const float*)d_in[2];
  const float* Wv         = (const float*)d_in[3];
  const float* Wo         = (const float*)d_in[4];
  const float* bo         = (const float*)d_in[5];
  const float* bias_table = (const float*)d_in[6];
  float* out = (float*)d_out;

  char* ws = (char*)d_ws;
  u16* xb   = (u16*)(ws);                      // xb dead after QKV GEMM -> reused for gb4
  u16* wqb  = (u16*)(ws + 16777216);           // Wq,Wk,Wv,Wo bf16 contiguous
  u16* wob  = (u16*)(ws + 16777216 + 3 * 2097152);
  u16* qb   = (u16*)(ws + 25165824);           // q/k/v(t) contiguous, 16 MB each
  u16* kb   = qb + 8388608;
  u16* vtb  = kb + 8388608;                    // V stored [B,H,hd,S] as fp16
  u16* ctxb = (u16*)(ws + 75497472);
  f32x4* gb4 = (f32x4*)(ws);                   // 1MB, overlays dead xb

  cvt_f2b_kernel<<<8192, 256, 0, stream>>>(x, xb, 8388608);
  cvtw_kernel<<<dim3(1024, 4), 256, 0, stream>>>(Wq, Wk, Wv, Wo, wqb);

  gemm128_bt<0><<<dim3(64, 8, 3), 256, 0, stream>>>(
      xb, wqb, (void*)qb, nullptr, 8192, 1024, 1024);

  bias4x_kernel<<<256, 256, 0, stream>>>(bias_table, gb4);

  attn_mfma_kernel<<<dim3(64, 8), 256, 0, stream>>>(qb, kb, vtb, gb4, ctxb);

  gemm128_bt<1><<<dim3(64, 8), 256, 0, stream>>>(
      ctxb, wob, (void*)out, bo, 8192, 1024, 1024);
}

// Round 9
// 278.200 us; speedup vs baseline: 5.1230x; 1.0462x over previous
//
#include <hip/hip_runtime.h>
#include <string.h>

typedef unsigned short u16;
typedef unsigned int   u32;
typedef __attribute__((ext_vector_type(8))) short short8;     // 8 bf16/fp16 = 4 VGPRs
typedef __attribute__((ext_vector_type(4))) float f32x4;
typedef __attribute__((ext_vector_type(16))) float f32x16;
typedef __attribute__((ext_vector_type(2))) __fp16 h2;
typedef __attribute__((ext_vector_type(8))) __fp16 h8;
typedef __attribute__((ext_vector_type(2))) unsigned int u32x2;

// ---------- helpers ----------
__device__ __forceinline__ u16 f2b(float f) {                 // fp32 -> bf16 (RNE)
  u32 u = __float_as_uint(f);
  u32 r = (u + 0x7fffu + ((u >> 16) & 1u)) >> 16;
  return (u16)r;
}
// async global->LDS, 16B per lane; LDS dest = wave-uniform base + lane*16
__device__ __forceinline__ void cp16(const u16* g, u16* l) {
  __builtin_amdgcn_global_load_lds(
      (const __attribute__((address_space(1))) void*)g,
      (__attribute__((address_space(3))) void*)l, 16, 0, 0);
}
// v_permlane32_swap: a' = {a.lo32 | b.lo32}, b' = {a.hi32 | b.hi32}
__device__ __forceinline__ void plswap(u32& a, u32& b) {
  u32x2 r = __builtin_amdgcn_permlane32_swap(a, b, false, false);
  a = r[0]; b = r[1];
}

// ---------- fused prep: x -> bf16 (blocks 0..8191), W0..W3 -> bf16 (8192..12287) ----------
__global__ __launch_bounds__(256) void prep_kernel(
    const float* __restrict__ x,
    const float* __restrict__ w0, const float* __restrict__ w1,
    const float* __restrict__ w2, const float* __restrict__ w3,
    u16* __restrict__ xb, u16* __restrict__ wqb) {
  int bid = blockIdx.x;
  if (bid < 8192) {
    int i = (bid * 256 + threadIdx.x) * 4;
    float4 v = *(const float4*)&x[i];
    *(ushort4*)&xb[i] = make_ushort4(f2b(v.x), f2b(v.y), f2b(v.z), f2b(v.w));
  } else {
    bid -= 8192;
    const int wsel = bid >> 10;
    const float* src = (wsel == 0) ? w0 : (wsel == 1) ? w1 : (wsel == 2) ? w2 : w3;
    int i = ((bid & 1023) * 256 + threadIdx.x) * 4;
    float4 v = *(const float4*)&src[i];
    *(ushort4*)&wqb[((size_t)wsel << 20) + i] =
        make_ushort4(f2b(v.x), f2b(v.y), f2b(v.z), f2b(v.w));
  }
}

// ---------- bias4 expansion: gb4[h][j] = {bt[j-3..j]} * log2(e), clamped ----------
// runs AFTER the QKV GEMM (gb4 overlays the then-dead xb region)
__global__ __launch_bounds__(256) void bias4x_kernel(const float* __restrict__ bt,
                                                     f32x4* __restrict__ gb4) {
  int idx = blockIdx.x * 256 + threadIdx.x;   // grid 256 -> 65536 = 16 heads x 4096
  int h = idx >> 12, j = idx & 4095;
  f32x4 v;
  #pragma unroll
  for (int e = 0; e < 4; ++e) {
    int r = j - 3 + e;
    r = r < 0 ? 0 : (r > 4094 ? 4094 : r);
    v[e] = bt[r * 16 + h] * 1.44269504f;
  }
  gb4[idx] = v;
}

// ---------- bf16 MFMA GEMM, BK=32, single-barrier dbuf pipeline (r3-exact) ----------
template<int MODE>
__global__ __launch_bounds__(256) void gemm128_bt(
    const u16* __restrict__ A, const u16* __restrict__ Bw,
    void* __restrict__ outp, const float* __restrict__ bias,
    const int M, const int N, const int K) {
  __shared__ __attribute__((aligned(16))) u16 As[2][128 * 32];
  __shared__ __attribute__((aligned(16))) u16 Bs[2][128 * 32];

  const u16* Bw2 = Bw;
  if (MODE == 0) Bw2 += ((size_t)blockIdx.z) << 20;

  const int tid  = threadIdx.x;
  const int wave = tid >> 6, lane = tid & 63;
  const int quad = lane >> 4, l15 = lane & 15;
  const int wm   = (wave >> 1) * 64, wn = (wave & 1) * 64;
  const int m0   = blockIdx.x * 128, n0 = blockIdx.y * 128;

  const int srow = wave * 32 + (lane >> 2);
  const int scol = (lane & 3) * 8;
  const u16* gA0 = A   + (size_t)(m0 + srow) * K + scol;
  const u16* gA1 = gA0 + (size_t)16 * K;
  const u16* gB0 = Bw2 + (size_t)(n0 + srow) * K + scol;
  const u16* gB1 = gB0 + (size_t)16 * K;
  const int lo0 = (wave * 32) * 32, lo1 = (wave * 32 + 16) * 32;

  cp16(gA0, &As[0][lo0]); cp16(gA1, &As[0][lo1]);
  cp16(gB0, &Bs[0][lo0]); cp16(gB1, &Bs[0][lo1]);
  gA0 += 32; gA1 += 32; gB0 += 32; gB1 += 32;

  f32x4 acc[4][4] = {};
  const int nk = K >> 5;
  for (int kt = 0; kt < nk; ++kt) {
    const int cur = kt & 1;
    __syncthreads();
    if (kt + 1 < nk) {
      cp16(gA0, &As[1 - cur][lo0]); cp16(gA1, &As[1 - cur][lo1]);
      cp16(gB0, &Bs[1 - cur][lo0]); cp16(gB1, &Bs[1 - cur][lo1]);
      gA0 += 32; gA1 += 32; gB0 += 32; gB1 += 32;
    }
    short8 af[4], bf[4];
    #pragma unroll
    for (int mi = 0; mi < 4; ++mi)
      af[mi] = *(const short8*)&As[cur][(wm + mi * 16 + l15) * 32 + quad * 8];
    #pragma unroll
    for (int ni = 0; ni < 4; ++ni)
      bf[ni] = *(const short8*)&Bs[cur][(wn + ni * 16 + l15) * 32 + quad * 8];
    #pragma unroll
    for (int mi = 0; mi < 4; ++mi)
      #pragma unroll
      for (int ni = 0; ni < 4; ++ni)
        acc[mi][ni] = __builtin_amdgcn_mfma_f32_16x16x32_bf16(af[mi], bf[ni], acc[mi][ni], 0, 0, 0);
  }

  #pragma unroll
  for (int mi = 0; mi < 4; ++mi)
    #pragma unroll
    for (int ni = 0; ni < 4; ++ni) {
      if (MODE == 0 && blockIdx.z == 2) {
        int mb = m0 + wm + mi * 16 + quad * 4;
        int n  = n0 + wn + ni * 16 + l15;
        int b = mb >> 11, s = mb & 2047, h = n >> 6, d = n & 63;
        u16* out = (u16*)outp + (((size_t)2) << 23);
        h2 p0 = __builtin_amdgcn_cvt_pkrtz(acc[mi][ni][0], acc[mi][ni][1]);
        h2 p1 = __builtin_amdgcn_cvt_pkrtz(acc[mi][ni][2], acc[mi][ni][3]);
        ushort4 o;
        memcpy(&o.x, &p0, 4);
        memcpy(&o.z, &p1, 4);
        *(ushort4*)&out[((((size_t)b * 16 + h) * 64 + d) << 11) + s] = o;
      } else {
        #pragma unroll
        for (int r = 0; r < 4; ++r) {
          int m = m0 + wm + mi * 16 + quad * 4 + r;
          int n = n0 + wn + ni * 16 + l15;
          float v = acc[mi][ni][r];
          if (MODE == 0) {
            int b = m >> 11, s = m & 2047, h = n >> 6, d = n & 63;
            u16* out = (u16*)outp + (((size_t)blockIdx.z) << 23);
            out[((((size_t)b * 16 + h) * 2048 + s) << 6) + d] = f2b(v);
          } else {
            ((float*)outp)[(size_t)m * N + n] = v + bias[n];
          }
        }
      }
    }
}

// ---------- MFMA flash attention: r3-exact structure (proven 100.0 us) ----------
// Only change vs r3: the LDS bias4 table is built in ONE coalesced pass from the
// precomputed global gb4 (bias4[i] = gb4[h][q0+i+3] = {bt[q0+i .. q0+i+3]}),
// replacing r3's two-pass scalar build through a Ks[0] temp. Visibility is covered
// by the loop-top barrier of kt=0 (bias4 is first read after it) -> no extra barrier.
// Bias reads stay on the LDS/lgkmcnt path (r8 proved global bias couples into the
// vmcnt queue and stalls the cp16 pipeline: +19us).
__global__ __launch_bounds__(256, 2) void attn_mfma_kernel(
    const u16* __restrict__ qb, const u16* __restrict__ kb, const u16* __restrict__ vtb,
    const f32x4* __restrict__ gb4, u16* __restrict__ ctx) {
  __shared__ __attribute__((aligned(16))) u16 Ks[2][64 * 64];  // dbuf, XOR-swizzled
  __shared__ __attribute__((aligned(16))) u16 Vs[2][64 * 64];  // dbuf, [d][k] fp16, XOR-swizzled
  __shared__ __attribute__((aligned(16))) f32x4 bias4[2304];   // bias4[i] = {bt[q0+i..q0+i+3]}*log2e

  const int tid  = threadIdx.x;
  const int wave = tid >> 6, lane = tid & 63;
  const int l31  = lane & 31, hi = lane >> 5;
  const int xsw  = l31 & 7;
  const int bh   = blockIdx.x, h = bh & 15, b = bh >> 4;
  const int q0   = blockIdx.y * 256;

  // ---- build bias4 from gb4: one coalesced pass, 9 f32x4 per thread ----
  {
    const f32x4* gbh = gb4 + (h << 12);
    for (int i = tid; i < 2304; i += 256) {
      int j = q0 + i + 3; if (j > 4095) j = 4095;
      bias4[i] = gbh[j];
    }
  }

  // Q B-frags: n = q, k(=d) = ks*16 + hi*8 + j
  short8 aQ[2][4];
  #pragma unroll
  for (int qs = 0; qs < 2; ++qs)
    #pragma unroll
    for (int ks = 0; ks < 4; ++ks)
      aQ[qs][ks] = *(const short8*)&qb[((size_t)bh * 2048 + q0 + wave * 64 + qs * 32 + l31) * 64
                                       + ks * 16 + hi * 8];

  f32x16 accO[2][2] = {};   // [qs][dt]; row d = (r&3)+8*(r>>2)+4*hi+32*dt, col q = l31
  f32x16 accL[2]    = {};   // lsum via ones-MFMA; accL[qs][0] = full k-sum for col q

  const h8 ones8 = {(__fp16)1.f, (__fp16)1.f, (__fp16)1.f, (__fp16)1.f,
                    (__fp16)1.f, (__fp16)1.f, (__fp16)1.f, (__fp16)1.f};

  // K staging (global_load_lds, pre-swizzled global source)
  const int krow = lane >> 3;
  const int kchk = (lane & 7) ^ krow;
  const u16* kbase = kb + (((size_t)bh * 2048) << 6);

  // V staging via regs -> swizzled LDS writes
  const int srow = tid >> 2, t0 = tid & 3, ssw = srow & 7;
  const u16* vrow = vtb + (((size_t)bh * 64 + srow) << 11) + t0 * 16;
  const int vo0 = srow * 64 + (((2 * t0    ) ^ ssw) << 3);
  const int vo1 = srow * 64 + (((2 * t0 + 1) ^ ssw) << 3);

  // prologue: stage tile 0, prefetch tile 1 regs
  short8 vpre0 = *(const short8*)&vrow[0];
  short8 vpre1 = *(const short8*)&vrow[8];
  *(short8*)&Vs[0][vo0] = vpre0;           // compiler inserts vmcnt wait
  *(short8*)&Vs[0][vo1] = vpre1;
  #pragma unroll
  for (int g = 0; g < 2; ++g)
    cp16(kbase + (size_t)(wave * 16 + g * 8 + krow) * 64 + kchk * 8,
         &Ks[0][(wave * 16 + g * 8) * 64]);
  vpre0 = *(const short8*)&vrow[64];
  vpre1 = *(const short8*)&vrow[72];

  for (int kt = 0; kt < 32; ++kt) {
    const int cur = kt & 1;
    __syncthreads();   // drains cp16(kt) + vpre loads; makes Vs[cur] (and bias4) visible
    if (kt < 31) {
      #pragma unroll
      for (int g = 0; g < 2; ++g)
        cp16(kbase + (size_t)((kt + 1) * 64 + wave * 16 + g * 8 + krow) * 64 + kchk * 8,
             &Ks[1 - cur][(wave * 16 + g * 8) * 64]);
      *(short8*)&Vs[1 - cur][vo0] = vpre0;   // V(kt+1), already landed (drained at barrier)
      *(short8*)&Vs[1 - cur][vo1] = vpre1;
      if (kt < 30) {
        const u16* vp = vrow + ((size_t)(kt + 2) << 6);
        vpre0 = *(const short8*)&vp[0];
        vpre1 = *(const short8*)&vp[8];
      }
    }

    #pragma unroll
    for (int t = 0; t < 2; ++t) {
      // ---- S^T tile t: rows k = t*32 + row(r,hi), cols q; aK shared across qs ----
      short8 aK[4];
      #pragma unroll
      for (int ks = 0; ks < 4; ++ks)
        aK[ks] = *(const short8*)&Ks[cur][(t * 32 + l31) * 64
                                          + (((ks * 2 + hi) ^ xsw) << 3)];
      f32x16 accS[2] = {};
      __builtin_amdgcn_s_setprio(1);
      #pragma unroll
      for (int ks = 0; ks < 4; ++ks)
        #pragma unroll
        for (int qs = 0; qs < 2; ++qs)
          accS[qs] = __builtin_amdgcn_mfma_f32_32x32x16_bf16(aK[ks], aQ[qs][ks], accS[qs], 0, 0, 0);
      __builtin_amdgcn_s_setprio(0);

      // ---- softmax: p = exp2(S*log2e/8 + bias*log2e); one LDS b128 bias read per rg ----
      u32 d[2][8];
      #pragma unroll
      for (int qs = 0; qs < 2; ++qs) {
        // bias4[ib3-8rg][3-j] = bt[q - (k-row) + 2047] for accS elem 4rg+j
        const int ib3 = wave * 64 + qs * 32 + l31 - kt * 64 - t * 32 - 4 * hi + 2044;
        #pragma unroll
        for (int rg = 0; rg < 4; ++rg) {
          const f32x4 bb4 = bias4[ib3 - 8 * rg];   // [0]=bias(J-3) .. [3]=bias(J)
          float p0 = __builtin_amdgcn_exp2f(fmaf(accS[qs][4 * rg + 0], 0.18033688f, bb4[3]));
          float p1 = __builtin_amdgcn_exp2f(fmaf(accS[qs][4 * rg + 1], 0.18033688f, bb4[2]));
          float p2 = __builtin_amdgcn_exp2f(fmaf(accS[qs][4 * rg + 2], 0.18033688f, bb4[1]));
          float p3 = __builtin_amdgcn_exp2f(fmaf(accS[qs][4 * rg + 3], 0.18033688f, bb4[0]));
          h2 e0; e0[0] = (__fp16)p0; e0[1] = (__fp16)p1;
          h2 e1; e1[0] = (__fp16)p2; e1[1] = (__fp16)p3;
          memcpy(&d[qs][2 * rg],     &e0, 4);
          memcpy(&d[qs][2 * rg + 1], &e1, 4);
        }
      }

      // ---- PV + lsum: V reads shared across qs; lsum on MFMA pipe ----
      #pragma unroll
      for (int sl = 0; sl < 2; ++sl) {
        const int ch = ((t * 2 + sl) * 2 + hi) ^ xsw;   // k-chunk for this step
        short8 av0 = *(const short8*)&Vs[cur][(     l31) * 64 + (ch << 3)];
        short8 av1 = *(const short8*)&Vs[cur][(32 + l31) * 64 + (ch << 3)];
        h8 avh0, avh1;
        memcpy(&avh0, &av0, 16);
        memcpy(&avh1, &av1, 16);
        __builtin_amdgcn_s_setprio(1);
        #pragma unroll
        for (int qs = 0; qs < 2; ++qs) {
          u32 F0 = d[qs][4 * sl], F1 = d[qs][4 * sl + 1];
          u32 F2 = d[qs][4 * sl + 2], F3 = d[qs][4 * sl + 3];
          plswap(F0, F2);
          plswap(F1, F3);
          union { u32 w[4]; h8 v; } uf;
          uf.w[0] = F0; uf.w[1] = F1; uf.w[2] = F2; uf.w[3] = F3;
          accO[qs][0] = __builtin_amdgcn_mfma_f32_32x32x16_f16(avh0, uf.v, accO[qs][0], 0, 0, 0);
          accO[qs][1] = __builtin_amdgcn_mfma_f32_32x32x16_f16(avh1, uf.v, accO[qs][1], 0, 0, 0);
          accL[qs]    = __builtin_amdgcn_mfma_f32_32x32x16_f16(ones8, uf.v, accL[qs], 0, 0, 0);
        }
        __builtin_amdgcn_s_setprio(0);
      }
    }
  }

  // ---- epilogue: accL[qs][0] already holds the full k-sum for col q ----
  #pragma unroll
  for (int qs = 0; qs < 2; ++qs) {
    const float inv = 1.0f / accL[qs][0];
    const int q = q0 + wave * 64 + qs * 32 + l31;
    #pragma unroll
    for (int dt = 0; dt < 2; ++dt)
      #pragma unroll
      for (int rg = 0; rg < 4; ++rg) {
        ushort4 o = make_ushort4(f2b(accO[qs][dt][4 * rg + 0] * inv), f2b(accO[qs][dt][4 * rg + 1] * inv),
                                 f2b(accO[qs][dt][4 * rg + 2] * inv), f2b(accO[qs][dt][4 * rg + 3] * inv));
        *(ushort4*)&ctx[((size_t)b * 2048 + q) * 1024 + h * 64 + dt * 32 + rg * 8 + hi * 4] = o;
      }
  }
}

// ---------- launch ----------
extern "C" void kernel_launch(void* const* d_in, const int* in_sizes, int n_in,
                              void* d_out, int out_size, void* d_ws, size_t ws_size,
                              hipStream_t stream) {
  const float* x          = (const float*)d_in[0];
  const float* Wq         = (const float*)d_in[1];
  const float* Wk         = (const float*)d_in[2];
  const float* Wv         = (const float*)d_in[3];
  const float* Wo         = (const float*)d_in[4];
  const float* bo         = (const float*)d_in[5];
  const float* bias_table = (const float*)d_in[6];
  float* out = (float*)d_out;

  char* ws = (char*)d_ws;
  u16* xb   = (u16*)(ws);                      // xb dead after QKV GEMM -> reused for gb4
  u16* wqb  = (u16*)(ws + 16777216);           // Wq,Wk,Wv,Wo bf16 contiguous
  u16* wob  = (u16*)(ws + 16777216 + 3 * 2097152);
  u16* qb   = (u16*)(ws + 25165824);           // q/k/v(t) contiguous, 16 MB each
  u16* kb   = qb + 8388608;
  u16* vtb  = kb + 8388608;                    // V stored [B,H,hd,S] as fp16
  u16* ctxb = (u16*)(ws + 75497472);
  f32x4* gb4 = (f32x4*)(ws);                   // 1MB, overlays dead xb

  prep_kernel<<<12288, 256, 0, stream>>>(x, Wq, Wk, Wv, Wo, xb, wqb);

  gemm128_bt<0><<<dim3(64, 8, 3), 256, 0, stream>>>(
      xb, wqb, (void*)qb, nullptr, 8192, 1024, 1024);

  bias4x_kernel<<<256, 256, 0, stream>>>(bias_table, gb4);

  attn_mfma_kernel<<<dim3(64, 8), 256, 0, stream>>>(qb, kb, vtb, gb4, ctxb);

  gemm128_bt<1><<<dim3(64, 8), 256, 0, stream>>>(
      ctxb, wob, (void*)out, bo, 8192, 1024, 1024);
}

// Round 10
// 277.327 us; speedup vs baseline: 5.1392x; 1.0031x over previous
//
#include <hip/hip_runtime.h>
#include <string.h>

typedef unsigned short u16;
typedef unsigned int   u32;
typedef __attribute__((ext_vector_type(8))) short short8;     // 8 bf16/fp16 = 4 VGPRs
typedef __attribute__((ext_vector_type(4))) float f32x4;
typedef __attribute__((ext_vector_type(16))) float f32x16;
typedef __attribute__((ext_vector_type(2))) __fp16 h2;
typedef __attribute__((ext_vector_type(8))) __fp16 h8;
typedef __attribute__((ext_vector_type(2))) unsigned int u32x2;

// ---------- helpers ----------
__device__ __forceinline__ u16 f2b(float f) {                 // fp32 -> bf16 (RNE)
  u32 u = __float_as_uint(f);
  u32 r = (u + 0x7fffu + ((u >> 16) & 1u)) >> 16;
  return (u16)r;
}
// async global->LDS, 16B per lane; LDS dest = wave-uniform base + lane*16
__device__ __forceinline__ void cp16(const u16* g, u16* l) {
  __builtin_amdgcn_global_load_lds(
      (const __attribute__((address_space(1))) void*)g,
      (__attribute__((address_space(3))) void*)l, 16, 0, 0);
}
// v_permlane32_swap: a' = {a.lo32 | b.lo32}, b' = {a.hi32 | b.hi32}
__device__ __forceinline__ void plswap(u32& a, u32& b) {
  u32x2 r = __builtin_amdgcn_permlane32_swap(a, b, false, false);
  a = r[0]; b = r[1];
}

// ---------- fused prep: x -> bf16 (blocks 0..8191), W0..W3 -> bf16 (8192..12287) ----------
__global__ __launch_bounds__(256) void prep_kernel(
    const float* __restrict__ x,
    const float* __restrict__ w0, const float* __restrict__ w1,
    const float* __restrict__ w2, const float* __restrict__ w3,
    u16* __restrict__ xb, u16* __restrict__ wqb) {
  int bid = blockIdx.x;
  if (bid < 8192) {
    int i = (bid * 256 + threadIdx.x) * 4;
    float4 v = *(const float4*)&x[i];
    *(ushort4*)&xb[i] = make_ushort4(f2b(v.x), f2b(v.y), f2b(v.z), f2b(v.w));
  } else {
    bid -= 8192;
    const int wsel = bid >> 10;
    const float* src = (wsel == 0) ? w0 : (wsel == 1) ? w1 : (wsel == 2) ? w2 : w3;
    int i = ((bid & 1023) * 256 + threadIdx.x) * 4;
    float4 v = *(const float4*)&src[i];
    *(ushort4*)&wqb[((size_t)wsel << 20) + i] =
        make_ushort4(f2b(v.x), f2b(v.y), f2b(v.z), f2b(v.w));
  }
}

// ---------- bias4 expansion: gb4[h][j] = {bt[j-3..j]} * log2(e), clamped ----------
__global__ __launch_bounds__(256) void bias4x_kernel(const float* __restrict__ bt,
                                                     f32x4* __restrict__ gb4) {
  int idx = blockIdx.x * 256 + threadIdx.x;   // grid 256 -> 65536 = 16 heads x 4096
  int h = idx >> 12, j = idx & 4095;
  f32x4 v;
  #pragma unroll
  for (int e = 0; e < 4; ++e) {
    int r = j - 3 + e;
    r = r < 0 ? 0 : (r > 4094 ? 4094 : r);
    v[e] = bt[r * 16 + h] * 1.44269504f;
  }
  gb4[idx] = v;
}

// ---------- bf16 MFMA GEMM: 256x128 tile, BK=64, 3-buf depth-2 pipeline ----------
// T3/T4: raw s_barrier + counted "s_waitcnt vmcnt(6)" at iter top -- next tile's 6
// staging loads stay in flight across the barrier (no vmcnt(0) drain until t=15).
// T2: LDS rows are 128B (worst-case bank geometry) -> chunk ^= row&7 swizzle in
// 16B units, applied as pre-swizzled global_load_lds SOURCE + swizzled ds_read
// (the exact proven pattern from the attn K staging).
// T5: setprio(1) around each 8-MFMA phase cluster.
// 512 threads = 8 waves (4M x 2N), per-wave 64x64 C (4x4 16x16x32 frags) -- same
// frag geometry and epilogues as the previous 128^2 kernel.
template<int MODE>
__global__ __launch_bounds__(512, 1) void gemm256_bt(
    const u16* __restrict__ A, const u16* __restrict__ Bw,
    void* __restrict__ outp, const float* __restrict__ bias,
    const int M, const int N, const int K) {
  __shared__ __attribute__((aligned(16))) u16 smem[3 * 24576];  // 144KB: 3x(A 16K + B 8K elems)

  const u16* Bw2 = Bw;
  if (MODE == 0) Bw2 += ((size_t)blockIdx.z) << 20;

  const int tid  = threadIdx.x;
  const int wave = tid >> 6, lane = tid & 63;
  const int quad = lane >> 4, l15 = lane & 15;
  const int wm   = (wave >> 1) * 64, wn = (wave & 1) * 64;
  const int m0   = blockIdx.x * 256, n0 = blockIdx.y * 128;

  // staging: per 64-row round, wave covers rows [wave*8, wave*8+8); lane>>3 = row,
  // lane&7 = dest chunk (8 elem). Source chunk pre-swizzled by row&7 (= lane>>3).
  const int srow8 = wave * 8 + (lane >> 3);
  const int schk  = ((lane & 7) ^ (lane >> 3)) * 8;
  const u16* gA[4]; const u16* gB[2];
  #pragma unroll
  for (int r = 0; r < 4; ++r) gA[r] = A   + (size_t)(m0 + r * 64 + srow8) * K + schk;
  #pragma unroll
  for (int r = 0; r < 2; ++r) gB[r] = Bw2 + (size_t)(n0 + r * 64 + srow8) * K + schk;

  auto STAGE = [&](int bufi) {
    u16* Ab = smem + bufi * 24576;
    u16* Bb = Ab + 16384;
    #pragma unroll
    for (int r = 0; r < 4; ++r) { cp16(gA[r], Ab + r * 4096 + wave * 512); gA[r] += 64; }
    #pragma unroll
    for (int r = 0; r < 2; ++r) { cp16(gB[r], Bb + r * 4096 + wave * 512); gB[r] += 64; }
  };

  f32x4 acc[4][4] = {};
  const int nk = K >> 6;      // 16 K-tiles
  STAGE(0); STAGE(1);         // prologue: tiles 0,1 in flight (12 loads)

  for (int t = 0; t < nk; ++t) {
    // tile t certified landed: this wave's 6 tile-t loads are older than the
    // (up to) 6 tile-(t+1) loads -> wait to <=6 outstanding; barrier makes it global.
    if (t + 1 < nk) asm volatile("s_waitcnt vmcnt(6)" ::: "memory");
    else            asm volatile("s_waitcnt vmcnt(0)" ::: "memory");
    __builtin_amdgcn_s_barrier();
    __builtin_amdgcn_sched_barrier(0);
    if (t + 2 < nk) STAGE((t + 2) % 3);          // into buf holding tile t-1 (reads done)

    const u16* Ab = smem + (t % 3) * 24576;
    const u16* Bb = Ab + 16384;
    #pragma unroll
    for (int ph = 0; ph < 4; ++ph) {             // C-quadrant phases
      const int mh = ph >> 1, nh = ph & 1;
      short8 af[2][2], bf[2][2];
      #pragma unroll
      for (int i = 0; i < 2; ++i) {
        const int ra = (wm + (mh * 2 + i) * 16 + l15) * 64;
        const int rb = (wn + (nh * 2 + i) * 16 + l15) * 64;
        #pragma unroll
        for (int ks = 0; ks < 2; ++ks) {
          const int ca = (((ks * 4 + quad) ^ (l15 & 7)) * 8);
          af[i][ks] = *(const short8*)&Ab[ra + ca];
          bf[i][ks] = *(const short8*)&Bb[rb + ca];
        }
      }
      asm volatile("s_waitcnt lgkmcnt(0)" ::: "memory");
      __builtin_amdgcn_sched_barrier(0);
      __builtin_amdgcn_s_setprio(1);
      #pragma unroll
      for (int i = 0; i < 2; ++i)
        #pragma unroll
        for (int j = 0; j < 2; ++j) {
          acc[mh*2+i][nh*2+j] = __builtin_amdgcn_mfma_f32_16x16x32_bf16(af[i][0], bf[j][0], acc[mh*2+i][nh*2+j], 0, 0, 0);
          acc[mh*2+i][nh*2+j] = __builtin_amdgcn_mfma_f32_16x16x32_bf16(af[i][1], bf[j][1], acc[mh*2+i][nh*2+j], 0, 0, 0);
        }
      __builtin_amdgcn_s_setprio(0);
    }
  }

  // ---- epilogues (identical math to the proven 128^2 kernel) ----
  #pragma unroll
  for (int mi = 0; mi < 4; ++mi)
    #pragma unroll
    for (int ni = 0; ni < 4; ++ni) {
      if (MODE == 0 && blockIdx.z == 2) {
        int mb = m0 + wm + mi * 16 + quad * 4;
        int n  = n0 + wn + ni * 16 + l15;
        int b = mb >> 11, s = mb & 2047, h = n >> 6, d = n & 63;
        u16* out = (u16*)outp + (((size_t)2) << 23);
        h2 p0 = __builtin_amdgcn_cvt_pkrtz(acc[mi][ni][0], acc[mi][ni][1]);
        h2 p1 = __builtin_amdgcn_cvt_pkrtz(acc[mi][ni][2], acc[mi][ni][3]);
        ushort4 o;
        memcpy(&o.x, &p0, 4);
        memcpy(&o.z, &p1, 4);
        *(ushort4*)&out[((((size_t)b * 16 + h) * 64 + d) << 11) + s] = o;
      } else {
        #pragma unroll
        for (int r = 0; r < 4; ++r) {
          int m = m0 + wm + mi * 16 + quad * 4 + r;
          int n = n0 + wn + ni * 16 + l15;
          float v = acc[mi][ni][r];
          if (MODE == 0) {
            int b = m >> 11, s = m & 2047, h = n >> 6, d = n & 63;
            u16* out = (u16*)outp + (((size_t)blockIdx.z) << 23);
            out[((((size_t)b * 16 + h) * 2048 + s) << 6) + d] = f2b(v);
          } else {
            ((float*)outp)[(size_t)m * N + n] = v + bias[n];
          }
        }
      }
    }
}

// ---------- MFMA flash attention: r3-exact structure (proven 100.0 us) ----------
__global__ __launch_bounds__(256, 2) void attn_mfma_kernel(
    const u16* __restrict__ qb, const u16* __restrict__ kb, const u16* __restrict__ vtb,
    const f32x4* __restrict__ gb4, u16* __restrict__ ctx) {
  __shared__ __attribute__((aligned(16))) u16 Ks[2][64 * 64];  // dbuf, XOR-swizzled
  __shared__ __attribute__((aligned(16))) u16 Vs[2][64 * 64];  // dbuf, [d][k] fp16, XOR-swizzled
  __shared__ __attribute__((aligned(16))) f32x4 bias4[2304];   // bias4[i] = {bt[q0+i..q0+i+3]}*log2e

  const int tid  = threadIdx.x;
  const int wave = tid >> 6, lane = tid & 63;
  const int l31  = lane & 31, hi = lane >> 5;
  const int xsw  = l31 & 7;
  const int bh   = blockIdx.x, h = bh & 15, b = bh >> 4;
  const int q0   = blockIdx.y * 256;

  // ---- build bias4 from gb4: one coalesced pass, 9 f32x4 per thread ----
  {
    const f32x4* gbh = gb4 + (h << 12);
    for (int i = tid; i < 2304; i += 256) {
      int j = q0 + i + 3; if (j > 4095) j = 4095;
      bias4[i] = gbh[j];
    }
  }

  // Q B-frags: n = q, k(=d) = ks*16 + hi*8 + j
  short8 aQ[2][4];
  #pragma unroll
  for (int qs = 0; qs < 2; ++qs)
    #pragma unroll
    for (int ks = 0; ks < 4; ++ks)
      aQ[qs][ks] = *(const short8*)&qb[((size_t)bh * 2048 + q0 + wave * 64 + qs * 32 + l31) * 64
                                       + ks * 16 + hi * 8];

  f32x16 accO[2][2] = {};   // [qs][dt]; row d = (r&3)+8*(r>>2)+4*hi+32*dt, col q = l31
  f32x16 accL[2]    = {};   // lsum via ones-MFMA; accL[qs][0] = full k-sum for col q

  const h8 ones8 = {(__fp16)1.f, (__fp16)1.f, (__fp16)1.f, (__fp16)1.f,
                    (__fp16)1.f, (__fp16)1.f, (__fp16)1.f, (__fp16)1.f};

  // K staging (global_load_lds, pre-swizzled global source)
  const int krow = lane >> 3;
  const int kchk = (lane & 7) ^ krow;
  const u16* kbase = kb + (((size_t)bh * 2048) << 6);

  // V staging via regs -> swizzled LDS writes
  const int srow = tid >> 2, t0 = tid & 3, ssw = srow & 7;
  const u16* vrow = vtb + (((size_t)bh * 64 + srow) << 11) + t0 * 16;
  const int vo0 = srow * 64 + (((2 * t0    ) ^ ssw) << 3);
  const int vo1 = srow * 64 + (((2 * t0 + 1) ^ ssw) << 3);

  // prologue: stage tile 0, prefetch tile 1 regs
  short8 vpre0 = *(const short8*)&vrow[0];
  short8 vpre1 = *(const short8*)&vrow[8];
  *(short8*)&Vs[0][vo0] = vpre0;           // compiler inserts vmcnt wait
  *(short8*)&Vs[0][vo1] = vpre1;
  #pragma unroll
  for (int g = 0; g < 2; ++g)
    cp16(kbase + (size_t)(wave * 16 + g * 8 + krow) * 64 + kchk * 8,
         &Ks[0][(wave * 16 + g * 8) * 64]);
  vpre0 = *(const short8*)&vrow[64];
  vpre1 = *(const short8*)&vrow[72];

  for (int kt = 0; kt < 32; ++kt) {
    const int cur = kt & 1;
    __syncthreads();   // drains cp16(kt) + vpre loads; makes Vs[cur] (and bias4) visible
    if (kt < 31) {
      #pragma unroll
      for (int g = 0; g < 2; ++g)
        cp16(kbase + (size_t)((kt + 1) * 64 + wave * 16 + g * 8 + krow) * 64 + kchk * 8,
             &Ks[1 - cur][(wave * 16 + g * 8) * 64]);
      *(short8*)&Vs[1 - cur][vo0] = vpre0;   // V(kt+1), already landed (drained at barrier)
      *(short8*)&Vs[1 - cur][vo1] = vpre1;
      if (kt < 30) {
        const u16* vp = vrow + ((size_t)(kt + 2) << 6);
        vpre0 = *(const short8*)&vp[0];
        vpre1 = *(const short8*)&vp[8];
      }
    }

    #pragma unroll
    for (int t = 0; t < 2; ++t) {
      // ---- S^T tile t: rows k = t*32 + row(r,hi), cols q; aK shared across qs ----
      short8 aK[4];
      #pragma unroll
      for (int ks = 0; ks < 4; ++ks)
        aK[ks] = *(const short8*)&Ks[cur][(t * 32 + l31) * 64
                                          + (((ks * 2 + hi) ^ xsw) << 3)];
      f32x16 accS[2] = {};
      __builtin_amdgcn_s_setprio(1);
      #pragma unroll
      for (int ks = 0; ks < 4; ++ks)
        #pragma unroll
        for (int qs = 0; qs < 2; ++qs)
          accS[qs] = __builtin_amdgcn_mfma_f32_32x32x16_bf16(aK[ks], aQ[qs][ks], accS[qs], 0, 0, 0);
      __builtin_amdgcn_s_setprio(0);

      // ---- softmax: p = exp2(S*log2e/8 + bias*log2e); one LDS b128 bias read per rg ----
      u32 d[2][8];
      #pragma unroll
      for (int qs = 0; qs < 2; ++qs) {
        // bias4[ib3-8rg][3-j] = bt[q - (k-row) + 2047] for accS elem 4rg+j
        const int ib3 = wave * 64 + qs * 32 + l31 - kt * 64 - t * 32 - 4 * hi + 2044;
        #pragma unroll
        for (int rg = 0; rg < 4; ++rg) {
          const f32x4 bb4 = bias4[ib3 - 8 * rg];   // [0]=bias(J-3) .. [3]=bias(J)
          float p0 = __builtin_amdgcn_exp2f(fmaf(accS[qs][4 * rg + 0], 0.18033688f, bb4[3]));
          float p1 = __builtin_amdgcn_exp2f(fmaf(accS[qs][4 * rg + 1], 0.18033688f, bb4[2]));
          float p2 = __builtin_amdgcn_exp2f(fmaf(accS[qs][4 * rg + 2], 0.18033688f, bb4[1]));
          float p3 = __builtin_amdgcn_exp2f(fmaf(accS[qs][4 * rg + 3], 0.18033688f, bb4[0]));
          h2 e0; e0[0] = (__fp16)p0; e0[1] = (__fp16)p1;
          h2 e1; e1[0] = (__fp16)p2; e1[1] = (__fp16)p3;
          memcpy(&d[qs][2 * rg],     &e0, 4);
          memcpy(&d[qs][2 * rg + 1], &e1, 4);
        }
      }

      // ---- PV + lsum: V reads shared across qs; lsum on MFMA pipe ----
      #pragma unroll
      for (int sl = 0; sl < 2; ++sl) {
        const int ch = ((t * 2 + sl) * 2 + hi) ^ xsw;   // k-chunk for this step
        short8 av0 = *(const short8*)&Vs[cur][(     l31) * 64 + (ch << 3)];
        short8 av1 = *(const short8*)&Vs[cur][(32 + l31) * 64 + (ch << 3)];
        h8 avh0, avh1;
        memcpy(&avh0, &av0, 16);
        memcpy(&avh1, &av1, 16);
        __builtin_amdgcn_s_setprio(1);
        #pragma unroll
        for (int qs = 0; qs < 2; ++qs) {
          u32 F0 = d[qs][4 * sl], F1 = d[qs][4 * sl + 1];
          u32 F2 = d[qs][4 * sl + 2], F3 = d[qs][4 * sl + 3];
          plswap(F0, F2);
          plswap(F1, F3);
          union { u32 w[4]; h8 v; } uf;
          uf.w[0] = F0; uf.w[1] = F1; uf.w[2] = F2; uf.w[3] = F3;
          accO[qs][0] = __builtin_amdgcn_mfma_f32_32x32x16_f16(avh0, uf.v, accO[qs][0], 0, 0, 0);
          accO[qs][1] = __builtin_amdgcn_mfma_f32_32x32x16_f16(avh1, uf.v, accO[qs][1], 0, 0, 0);
          accL[qs]    = __builtin_amdgcn_mfma_f32_32x32x16_f16(ones8, uf.v, accL[qs], 0, 0, 0);
        }
        __builtin_amdgcn_s_setprio(0);
      }
    }
  }

  // ---- epilogue: accL[qs][0] already holds the full k-sum for col q ----
  #pragma unroll
  for (int qs = 0; qs < 2; ++qs) {
    const float inv = 1.0f / accL[qs][0];
    const int q = q0 + wave * 64 + qs * 32 + l31;
    #pragma unroll
    for (int dt = 0; dt < 2; ++dt)
      #pragma unroll
      for (int rg = 0; rg < 4; ++rg) {
        ushort4 o = make_ushort4(f2b(accO[qs][dt][4 * rg + 0] * inv), f2b(accO[qs][dt][4 * rg + 1] * inv),
                                 f2b(accO[qs][dt][4 * rg + 2] * inv), f2b(accO[qs][dt][4 * rg + 3] * inv));
        *(ushort4*)&ctx[((size_t)b * 2048 + q) * 1024 + h * 64 + dt * 32 + rg * 8 + hi * 4] = o;
      }
  }
}

// ---------- launch ----------
extern "C" void kernel_launch(void* const* d_in, const int* in_sizes, int n_in,
                              void* d_out, int out_size, void* d_ws, size_t ws_size,
                              hipStream_t stream) {
  const float* x          = (const float*)d_in[0];
  const float* Wq         = (const float*)d_in[1];
  const float* Wk         = (const float*)d_in[2];
  const float* Wv         = (const float*)d_in[3];
  const float* Wo         = (const float*)d_in[4];
  const float* bo         = (const float*)d_in[5];
  const float* bias_table = (const float*)d_in[6];
  float* out = (float*)d_out;

  char* ws = (char*)d_ws;
  u16* xb   = (u16*)(ws);                      // xb dead after QKV GEMM -> reused for gb4
  u16* wqb  = (u16*)(ws + 16777216);           // Wq,Wk,Wv,Wo bf16 contiguous
  u16* wob  = (u16*)(ws + 16777216 + 3 * 2097152);
  u16* qb   = (u16*)(ws + 25165824);           // q/k/v(t) contiguous, 16 MB each
  u16* kb   = qb + 8388608;
  u16* vtb  = kb + 8388608;                    // V stored [B,H,hd,S] as fp16
  u16* ctxb = (u16*)(ws + 75497472);
  f32x4* gb4 = (f32x4*)(ws);                   // 1MB, overlays dead xb

  prep_kernel<<<12288, 256, 0, stream>>>(x, Wq, Wk, Wv, Wo, xb, wqb);

  gemm256_bt<0><<<dim3(32, 8, 3), 512, 0, stream>>>(
      xb, wqb, (void*)qb, nullptr, 8192, 1024, 1024);

  bias4x_kernel<<<256, 256, 0, stream>>>(bias_table, gb4);

  attn_mfma_kernel<<<dim3(64, 8), 256, 0, stream>>>(qb, kb, vtb, gb4, ctxb);

  gemm256_bt<1><<<dim3(32, 8), 512, 0, stream>>>(
      ctxb, wob, (void*)out, bo, 8192, 1024, 1024);
}